// Round 14
// baseline (516.630 us; speedup 1.0000x reference)
//
#include <hip/hip_runtime.h>
#include <hip/hip_bf16.h>
#include <math.h>

// Problem constants
constexpr int kB   = 2;
constexpr int kS   = 2048;
constexpr int kD   = 1024;
constexpr int kFFN = 4096;
constexpr int kM   = kB * kS;      // 4096 tokens
constexpr int kH   = 8;
constexpr int kDH  = 128;
constexpr int kNC  = 64;           // scan chunks
constexpr int kT   = kS / kNC;     // 32 steps per chunk
constexpr int kNE  = 12288;        // 4 experts x 3072 packed N

typedef unsigned short u16;
typedef __attribute__((ext_vector_type(8))) short short8;
typedef __attribute__((ext_vector_type(4))) float f32x4;

__device__ __forceinline__ float sigf(float x) { return 1.0f / (1.0f + __expf(-x)); }
__device__ __forceinline__ float bu2f(u16 u) { return __uint_as_float(((unsigned)u) << 16); }
__device__ __forceinline__ u16 f2bu(float f) {
    __hip_bfloat16 h = __float2bfloat16(f);
    return reinterpret_cast<u16&>(h);
}
__device__ __forceinline__ void async16(const void* g, void* l) {
    __builtin_amdgcn_global_load_lds((const __attribute__((address_space(1))) void*)g,
                                     (__attribute__((address_space(3))) void*)l, 16, 0, 0);
}
// bijective XCD swizzle (m204)
__device__ __forceinline__ int xcd_swz(int orig, int nwg) {
    const int xcd = orig & 7;
    const int q8 = nwg >> 3, r8 = nwg & 7;
    return (xcd < r8 ? xcd * (q8 + 1) : r8 * (q8 + 1) + (xcd - r8) * q8) + (orig >> 3);
}

// ---------------- RMSNorm: f32 in, bf16 out ---------------------------------
__global__ __launch_bounds__(256) void rmsnorm_k(const float* __restrict__ x,
                                                 const float* __restrict__ w,
                                                 u16* __restrict__ o)
{
    __shared__ float red[4];
    const int row = blockIdx.x;
    const int t = threadIdx.x;
    float4 v = ((const float4*)(x + (size_t)row * kD))[t];
    float ss = v.x*v.x + v.y*v.y + v.z*v.z + v.w*v.w;
    #pragma unroll
    for (int m = 32; m; m >>= 1) ss += __shfl_xor(ss, m);
    if ((t & 63) == 0) red[t >> 6] = ss;
    __syncthreads();
    float tot = red[0] + red[1] + red[2] + red[3];
    float r = rsqrtf(tot * (1.0f / (float)kD) + 1e-6f);
    float4 wv = ((const float4*)w)[t];
    ushort4 u;
    u.x = f2bu(v.x * r * wv.x); u.y = f2bu(v.y * r * wv.y);
    u.z = f2bu(v.z * r * wv.z); u.w = f2bu(v.w * r * wv.w);
    ((ushort4*)(o + (size_t)row * kD))[t] = u;
}

// ---------------- Routing: pure f32 from x (top-k must not see bf16) --------
__global__ __launch_bounds__(64) void routing_k(const float* __restrict__ x,
                                                const float* __restrict__ wmix,
                                                const float* __restrict__ gw,
                                                float* __restrict__ wts,
                                                int* __restrict__ idx)
{
    const int row = blockIdx.x;
    const int lane = threadIdx.x;
    const float* xr = x + (size_t)row * kD;
    float ss = 0.0f;
    for (int d = lane; d < kD; d += 64) { float v = xr[d]; ss = fmaf(v, v, ss); }
    #pragma unroll
    for (int m = 32; m; m >>= 1) ss += __shfl_xor(ss, m);
    float r = rsqrtf(ss * (1.0f / (float)kD) + 1e-6f);

    float a0 = 0, a1 = 0, a2 = 0, a3 = 0;
    for (int d = lane; d < kD; d += 64) {
        float xv = xr[d] * wmix[d];
        float4 g = ((const float4*)gw)[d];
        a0 = fmaf(xv, g.x, a0);
        a1 = fmaf(xv, g.y, a1);
        a2 = fmaf(xv, g.z, a2);
        a3 = fmaf(xv, g.w, a3);
    }
    #pragma unroll
    for (int m = 32; m; m >>= 1) {
        a0 += __shfl_xor(a0, m);
        a1 += __shfl_xor(a1, m);
        a2 += __shfl_xor(a2, m);
        a3 += __shfl_xor(a3, m);
    }
    if (lane == 0) {
        float a[4] = {a0, a1, a2, a3};
        int i0 = 0; float v0 = a[0];
        #pragma unroll
        for (int e = 1; e < 4; ++e) if (a[e] > v0) { v0 = a[e]; i0 = e; }
        int i1 = -1; float v1 = -INFINITY;
        #pragma unroll
        for (int e = 0; e < 4; ++e) if (e != i0 && a[e] > v1) { v1 = a[e]; i1 = e; }
        float e1 = __expf(r * (v1 - v0));
        float dn = 1.0f + e1;
        wts[row * 2 + 0] = 1.0f / dn;
        wts[row * 2 + 1] = e1 / dn;
        idx[row * 2 + 0] = i0;
        idx[row * 2 + 1] = i1;
    }
}

// ---------------- Transpose-convert: f32 [rows][cols] -> bf16 [cols][rows] --
__global__ __launch_bounds__(256) void transp_k(const float* __restrict__ src,
                                                u16* __restrict__ dst,
                                                int rows, int cols,
                                                size_t sstride, size_t dstride)
{
    __shared__ float t[32][33];
    const float* s = src + blockIdx.z * sstride;
    u16* d = dst + blockIdx.z * dstride;
    const int c0 = blockIdx.x * 32, r0 = blockIdx.y * 32;
    const int tc = threadIdx.x & 31, tr4 = (threadIdx.x >> 5) * 4;
    #pragma unroll
    for (int i = 0; i < 4; ++i)
        t[tr4 + i][tc] = s[(size_t)(r0 + tr4 + i) * cols + c0 + tc];
    __syncthreads();
    #pragma unroll
    for (int i = 0; i < 4; ++i) {
        int cc = tr4 + i;
        d[(size_t)(c0 + cc) * rows + r0 + tc] = f2bu(t[tc][cc]);
    }
}

// ---------------- Bias pack: [12288] = e-major (bg|bv|bd) -------------------
__global__ __launch_bounds__(256) void biaspack_k(const float* __restrict__ bg,
                                                  const float* __restrict__ bv,
                                                  const float* __restrict__ bd,
                                                  float* __restrict__ pb)
{
    int e = blockIdx.y;
    int r = blockIdx.x * 256 + threadIdx.x;   // 0..3071
    const float* src = (r < 1024) ? bg : (r < 2048) ? bv : bd;
    pb[e * 3072 + r] = src[e * 1024 + (r & 1023)];
}

// ---------------- gemmA: BM=256 BN=256 BK=64, 8 waves (2Mx4N), per-wave 128x64
// ASYMMETRIC counted-vmcnt pipeline: A 3-deep (HBM/L3 stream, ~1200cyc cover),
// B 2-deep (L2-resident panel via M-fastest mapping). LDS = 3x32K + 2x32K =
// 163840 B (exact limit). Per-thread 4 A + 4 B loads/tile; issue order per iter
// B(t+1) then A(t+2); top-of-iter wait vmcnt(4) leaves only A(t+2) in flight
// => A(t), B(t) guaranteed landed. Buffer reuse barrier-protected.
template<bool BIAS, bool SILU, bool MUL>
__global__ __launch_bounds__(512, 1) void gemmA_k(
    const u16* __restrict__ A, const u16* __restrict__ BT,
    const float* __restrict__ bias, const u16* __restrict__ mulsrc,
    u16* __restrict__ Cout, int N, int K)
{
    __shared__ __align__(16) u16 ldsA[3][16384];   // 3 x A[256][64]
    __shared__ __align__(16) u16 ldsB[2][16384];   // 2 x B[256][64]
    const int tid = threadIdx.x;
    const int l = tid & 63;
    const int w = tid >> 6;                 // 0..7
    const int wr = w >> 2, wc = w & 3;      // 2M x 4N
    const int fr = l & 15, g = l >> 4;

    const int my = gridDim.y;               // M blocks
    const int wg = xcd_swz(blockIdx.y * gridDim.x + blockIdx.x, gridDim.x * my);
    const int bm = (wg % my) * 256, bn = (wg / my) * 256;   // M-fastest

    const int srow = l >> 3;
    const int scol = (l & 7) ^ srow;        // pre-swizzled source col-chunk
    const u16* gA = A  + (size_t)(bm + srow) * K + scol * 8;
    const u16* gB = BT + (size_t)(bn + srow) * K + scol * 8;

    auto STAGE_A = [&](int kt, int sb) {    // 4 async16 per thread
        u16* dst = ldsA[sb] + l * 8;
        const int k0 = kt * 64;
        #pragma unroll
        for (int i = 0; i < 4; ++i) {
            int chunk = w * 4 + i;
            async16(gA + (size_t)chunk * 8 * K + k0, dst + chunk * 512);
        }
    };
    auto STAGE_B = [&](int kt, int sb) {    // 4 async16 per thread
        u16* dst = ldsB[sb] + l * 8;
        const int k0 = kt * 64;
        #pragma unroll
        for (int i = 0; i < 4; ++i) {
            int chunk = w * 4 + i;
            async16(gB + (size_t)chunk * 8 * K + k0, dst + chunk * 512);
        }
    };

    f32x4 acc[8][4];
    #pragma unroll
    for (int m = 0; m < 8; ++m)
        #pragma unroll
        for (int n = 0; n < 4; ++n) acc[m][n] = (f32x4){0.f, 0.f, 0.f, 0.f};

    // prologue (issue order matters for vmcnt): B0, A0, A1
    STAGE_B(0, 0);
    STAGE_A(0, 0);
    STAGE_A(1, 1);
    const int nt = K >> 6;
    int cs = 0;
    for (int t = 0; t < nt; ++t) {
        // guarantee A(t), B(t) landed; keep A(t+2-1=next) in flight (4 loads)
        if (t + 1 < nt) asm volatile("s_waitcnt vmcnt(4)" ::: "memory");
        else            asm volatile("s_waitcnt vmcnt(0)" ::: "memory");
        __builtin_amdgcn_s_barrier();
        __builtin_amdgcn_sched_barrier(0);
        // B(t+1) -> ldsB[(t+1)&1]: last read in iter t-1, barrier-protected
        if (t + 1 < nt) STAGE_B(t + 1, (t + 1) & 1);
        // A(t+2) -> ldsA[(cs+2)%3]: last read in iter t-1, barrier-protected
        if (t + 2 < nt) {
            int ns = cs + 2; if (ns >= 3) ns -= 3;
            STAGE_A(t + 2, ns);
        }
        const u16* bA = ldsA[cs];
        const u16* bB = ldsB[t & 1];
        #pragma unroll
        for (int ks = 0; ks < 2; ++ks) {
            const int xo = ((ks * 4 + g) ^ (fr & 7)) * 8;
            short8 b[4];
            #pragma unroll
            for (int n = 0; n < 4; ++n)
                b[n] = *(const short8*)(bB + (wc * 64 + n * 16 + fr) * 64 + xo);
            #pragma unroll
            for (int m = 0; m < 8; ++m) {
                short8 a = *(const short8*)(bA + (wr * 128 + m * 16 + fr) * 64 + xo);
                #pragma unroll
                for (int n = 0; n < 4; ++n)
                    acc[m][n] = __builtin_amdgcn_mfma_f32_16x16x32_bf16(a, b[n], acc[m][n], 0, 0, 0);
            }
        }
        cs = (cs == 2) ? 0 : cs + 1;
    }

    const int orow0 = bm + wr * 128 + g * 4;
    const int ocol0 = bn + wc * 64 + fr;
    float bi[4];
    if constexpr (BIAS) {
        #pragma unroll
        for (int n = 0; n < 4; ++n) bi[n] = bias[ocol0 + n * 16];
    }
    #pragma unroll
    for (int m = 0; m < 8; ++m) {
        #pragma unroll
        for (int r = 0; r < 4; ++r) {
            const size_t ro = (size_t)(orow0 + m * 16 + r) * N;
            #pragma unroll
            for (int n = 0; n < 4; ++n) {
                const size_t off = ro + ocol0 + n * 16;
                float v = acc[m][n][r];
                if constexpr (BIAS) v += bi[n];
                if constexpr (SILU) v = v * sigf(v);
                if constexpr (MUL)  v *= bu2f(mulsrc[off]);
                Cout[off] = f2bu(v);
            }
        }
    }
}

// ---------------- gemmO: BM=256 BN=64 BK=64, 8 waves (4Mx2N), 2-stage --------
// Out-projection: f32 residual add, f32 out. LDS 80KB -> 2 blocks/CU.
__global__ __launch_bounds__(512, 2) void gemmO_k(
    const u16* __restrict__ A, const u16* __restrict__ BT,
    const float* __restrict__ res, float* __restrict__ Cout,
    int N, int K)
{
    __shared__ __align__(16) u16 lds[2][20480];   // per stage: A[256][64] | B[64][64]
    const int tid = threadIdx.x;
    const int l = tid & 63;
    const int w = tid >> 6;                 // 0..7
    const int wr = w >> 1, wc = w & 1;      // 4M x 2N; per-wave 64x32
    const int fr = l & 15, g = l >> 4;

    const int my = gridDim.y;
    const int wg = xcd_swz(blockIdx.y * gridDim.x + blockIdx.x, gridDim.x * my);
    const int bm = (wg % my) * 256, bn = (wg / my) * 64;    // M-fastest

    const int srow = l >> 3;
    const int scol = (l & 7) ^ srow;
    const u16* gA = A  + (size_t)(bm + srow) * K + scol * 8;
    const u16* gB = BT + (size_t)(bn + srow) * K + scol * 8;

    auto STAGE = [&](int kt, int sb) {
        u16* dst = lds[sb] + l * 8;
        const int k0 = kt * 64;
        #pragma unroll
        for (int i = 0; i < 4; ++i) {       // A: 32 chunks / 8 waves
            int chunk = w * 4 + i;
            async16(gA + (size_t)chunk * 8 * K + k0, dst + chunk * 512);
        }
        // B: 8 chunks / 8 waves (1 each)
        async16(gB + (size_t)w * 8 * K + k0, dst + 16384 + w * 512);
    };

    f32x4 acc[4][2];
    #pragma unroll
    for (int m = 0; m < 4; ++m)
        #pragma unroll
        for (int n = 0; n < 2; ++n) acc[m][n] = (f32x4){0.f, 0.f, 0.f, 0.f};

    STAGE(0, 0);
    __syncthreads();
    const int nt = K >> 6;
    for (int t = 0; t < nt; ++t) {
        const int cb = t & 1;
        if (t + 1 < nt) STAGE(t + 1, cb ^ 1);
        const u16* bA = lds[cb];
        const u16* bB = lds[cb] + 16384;
        #pragma unroll
        for (int ks = 0; ks < 2; ++ks) {
            const int xo = ((ks * 4 + g) ^ (fr & 7)) * 8;
            short8 a[4], b[2];
            #pragma unroll
            for (int m = 0; m < 4; ++m)
                a[m] = *(const short8*)(bA + (wr * 64 + m * 16 + fr) * 64 + xo);
            #pragma unroll
            for (int n = 0; n < 2; ++n)
                b[n] = *(const short8*)(bB + (wc * 32 + n * 16 + fr) * 64 + xo);
            #pragma unroll
            for (int m = 0; m < 4; ++m)
                #pragma unroll
                for (int n = 0; n < 2; ++n)
                    acc[m][n] = __builtin_amdgcn_mfma_f32_16x16x32_bf16(a[m], b[n], acc[m][n], 0, 0, 0);
        }
        __syncthreads();
    }

    const int orow0 = bm + wr * 64 + g * 4;
    const int ocol0 = bn + wc * 32 + fr;
    #pragma unroll
    for (int m = 0; m < 4; ++m) {
        #pragma unroll
        for (int r = 0; r < 4; ++r) {
            const size_t ro = (size_t)(orow0 + m * 16 + r) * N;
            #pragma unroll
            for (int n = 0; n < 2; ++n) {
                const size_t off = ro + ocol0 + n * 16;
                Cout[off] = acc[m][n][r] + res[off];
            }
        }
    }
}

// ---------------- minGRU chunked scan over gvdall [M][12288] ----------------
__global__ __launch_bounds__(256) void scan1_k(const u16* __restrict__ gvdall,
                                               float* __restrict__ sumA,
                                               float* __restrict__ sumX)
{
    const int e = blockIdx.y;
    int i = blockIdx.x * 256 + threadIdx.x;      // [0, kB*kNC*kD)
    int d = i & (kD - 1);
    int c = (i >> 10) & (kNC - 1);
    int b = i >> 16;
    const u16* gvd = gvdall + e * 3072;
    size_t base = ((size_t)b * kS + c * kT) * kNE + d;
    float A = 1.0f, X = 0.0f;
    for (int t = 0; t < kT; ++t) {
        size_t ix = base + (size_t)t * kNE;
        float xs = sigf(bu2f(gvd[ix])) * tanhf(bu2f(gvd[ix + 1024]));
        float a  = 0.001f + 0.998f * sigf(bu2f(gvd[ix + 2048]));
        A *= a;
        X = fmaf(a, X, xs);
    }
    size_t si = ((size_t)(e * kNC + c) * kB + b) * kD + d;
    sumA[si] = A;
    sumX[si] = X;
}

__global__ __launch_bounds__(256) void scan2_k(const float* __restrict__ sumA,
                                               const float* __restrict__ sumX,
                                               float* __restrict__ carry)
{
    const int e = blockIdx.y;
    int bd = blockIdx.x * 256 + threadIdx.x;     // [0, kB*kD)
    float h = 0.0f;
    for (int c = 0; c < kNC; ++c) {
        size_t si = ((size_t)(e * kNC + c)) * (kB * kD) + bd;
        carry[si] = h;
        h = fmaf(sumA[si], h, sumX[si]);
    }
}

// scan3: write h ONLY for the token's 2 selected experts (slot buffers)
__global__ __launch_bounds__(256) void scan3_k(const u16* __restrict__ gvdall,
                                               const float* __restrict__ carry,
                                               const int* __restrict__ tidx,
                                               u16* __restrict__ slot0,
                                               u16* __restrict__ slot1)
{
    const int e = blockIdx.y;
    int i = blockIdx.x * 256 + threadIdx.x;
    int d = i & (kD - 1);
    int c = (i >> 10) & (kNC - 1);
    int b = i >> 16;
    const u16* gvd = gvdall + e * 3072;
    size_t base = ((size_t)b * kS + c * kT) * kNE + d;
    float h = carry[((size_t)(e * kNC + c) * kB + b) * kD + d];
    const int tok0 = b * kS + c * kT;
    for (int t = 0; t < kT; ++t) {
        size_t ix = base + (size_t)t * kNE;
        float xs = sigf(bu2f(gvd[ix])) * tanhf(bu2f(gvd[ix + 1024]));
        float a  = 0.001f + 0.998f * sigf(bu2f(gvd[ix + 2048]));
        h = fmaf(a, h, xs);
        const int tok = tok0 + t;
        const size_t o = (size_t)tok * kD + d;
        if (e == tidx[tok * 2])          slot0[o] = f2bu(h);
        else if (e == tidx[tok * 2 + 1]) slot1[o] = f2bu(h);
    }
}

// ---------------- Fused MoE mix + attn RMSNorm -------------------------------
__global__ __launch_bounds__(256) void mixrms_k(const float* __restrict__ x,
                                                const u16* __restrict__ slot0,
                                                const u16* __restrict__ slot1,
                                                const float* __restrict__ wts,
                                                const float* __restrict__ w,
                                                float* __restrict__ xo,
                                                u16* __restrict__ xn)
{
    __shared__ float red[4];
    const int row = blockIdx.x;
    const int t = threadIdx.x;
    const size_t i = (size_t)row * 256 + t;     // float4 index
    float w0 = wts[row * 2 + 0], w1 = wts[row * 2 + 1];
    float4 xv = ((const float4*)x)[i];
    ushort4 h0 = ((const ushort4*)slot0)[i];
    ushort4 h1 = ((const ushort4*)slot1)[i];
    float4 o;
    o.x = xv.x + w0 * bu2f(h0.x) + w1 * bu2f(h1.x);
    o.y = xv.y + w0 * bu2f(h0.y) + w1 * bu2f(h1.y);
    o.z = xv.z + w0 * bu2f(h0.z) + w1 * bu2f(h1.z);
    o.w = xv.w + w0 * bu2f(h0.w) + w1 * bu2f(h1.w);
    ((float4*)xo)[i] = o;

    float ss = o.x*o.x + o.y*o.y + o.z*o.z + o.w*o.w;
    #pragma unroll
    for (int m = 32; m; m >>= 1) ss += __shfl_xor(ss, m);
    if ((t & 63) == 0) red[t >> 6] = ss;
    __syncthreads();
    float tot = red[0] + red[1] + red[2] + red[3];
    float r = rsqrtf(tot * (1.0f / (float)kD) + 1e-6f);
    float4 wv = ((const float4*)w)[t];
    ushort4 u;
    u.x = f2bu(o.x * r * wv.x); u.y = f2bu(o.y * r * wv.y);
    u.z = f2bu(o.z * r * wv.z); u.w = f2bu(o.w * r * wv.w);
    ((ushort4*)(xn + (size_t)row * kD))[t] = u;
}

// ---------------- V transpose: qkvb V-part -> vT [b*H+h][128 d][2048 s] -----
__global__ __launch_bounds__(256) void transpV_k(const u16* __restrict__ qkvb,
                                                 u16* __restrict__ vT)
{
    __shared__ u16 t[64][68];
    const int tid = threadIdx.x;
    const int s0 = blockIdx.x * 64;
    const int d0 = blockIdx.y * 64;
    const int bh = blockIdx.z;
    const int bb = bh >> 3, hh = bh & 7;
    const u16* src = qkvb + (size_t)(bb * kS + s0) * 3072 + 2048 + hh * kDH + d0;
    for (int idx = tid; idx < 64 * 16; idx += 256) {
        int sl = idx >> 4, c4 = (idx & 15) * 4;
        *(ushort4*)&t[sl][c4] = *(const ushort4*)(src + (size_t)sl * 3072 + c4);
    }
    __syncthreads();
    u16* dst = vT + ((size_t)bh * kDH + d0) * kS + s0;
    for (int idx = tid; idx < 64 * 16; idx += 256) {
        int dl = idx >> 4, s4 = (idx & 15) * 4;
        ushort4 v;
        v.x = t[s4 + 0][dl]; v.y = t[s4 + 1][dl];
        v.z = t[s4 + 2][dl]; v.w = t[s4 + 3][dl];
        *(ushort4*)(dst + (size_t)dl * kS + s4) = v;
    }
}

// ---------------- MFMA sliding-window attention ------------------------------
__global__ __launch_bounds__(256) void attn_mfma_k(const u16* __restrict__ qkvb,
                                                   const u16* __restrict__ vT,
                                                   u16* __restrict__ aob)
{
    __shared__ __align__(16) u16 KV[26112];      // K: [192][136] | VT: [128][200]
    __shared__ __align__(16) u16 P[4 * 16 * 200];

    const int tid = threadIdx.x;
    const int lane = tid & 63;
    const int w = tid >> 6;
    const int fr = lane & 15, g = lane >> 4;
    const int q0 = blockIdx.x * 64;
    const int hh = blockIdx.y;
    const int bb = blockIdx.z;
    const int kbase = q0 - 128;
    const float scale = 0.08838834764831845f;    // 1/sqrt(128)

    const u16* qkv_b = qkvb + (size_t)bb * kS * 3072 + hh * kDH;

    for (int idx = tid; idx < 192 * 16; idx += 256) {
        int k = idx >> 4, c = idx & 15;
        int kg = kbase + k; if (kg < 0) kg = 0;
        short8 v = *(const short8*)(qkv_b + (size_t)kg * 3072 + 1024 + c * 8);
        *(short8*)(&KV[k * 136 + c * 8]) = v;
    }
    short8 qf[4];
    {
        const u16* qrow = qkv_b + (size_t)(q0 + w * 16 + fr) * 3072 + g * 8;
        #pragma unroll
        for (int s = 0; s < 4; ++s) qf[s] = *(const short8*)(qrow + s * 32);
    }
    __syncthreads();

    f32x4 sacc[12];
    #pragma unroll
    for (int f = 0; f < 12; ++f) sacc[f] = (f32x4){0.f, 0.f, 0.f, 0.f};
    #pragma unroll
    for (int s = 0; s < 4; ++s) {
        #pragma unroll
        for (int f = 0; f < 12; ++f) {
            short8 bfr = *(const short8*)(&KV[(f * 16 + fr) * 136 + s * 32 + g * 8]);
            sacc[f] = __builtin_amdgcn_mfma_f32_16x16x32_bf16(qf[s], bfr, sacc[f], 0, 0, 0);
        }
    }

    float p[12][4];
    #pragma unroll
    for (int r = 0; r < 4; ++r) {
        const int ql = w * 16 + g * 4 + r;
        int kmin = 128 - q0; if (kmin < ql + 1) kmin = ql + 1;
        const int kmax = ql + 128;
        float mx = -1e30f;
        #pragma unroll
        for (int f = 0; f < 12; ++f) {
            int kl = f * 16 + fr;
            float sv = (kl >= kmin && kl <= kmax) ? sacc[f][r] * scale : -1e30f;
            p[f][r] = sv;
            mx = fmaxf(mx, sv);
        }
        mx = fmaxf(mx, __shfl_xor(mx, 1));
        mx = fmaxf(mx, __shfl_xor(mx, 2));
        mx = fmaxf(mx, __shfl_xor(mx, 4));
        mx = fmaxf(mx, __shfl_xor(mx, 8));
        float l = 0.f;
        #pragma unroll
        for (int f = 0; f < 12; ++f) { float e = __expf(p[f][r] - mx); p[f][r] = e; l += e; }
        l += __shfl_xor(l, 1);
        l += __shfl_xor(l, 2);
        l += __shfl_xor(l, 4);
        l += __shfl_xor(l, 8);
        float linv = 1.0f / l;
        #pragma unroll
        for (int f = 0; f < 12; ++f) p[f][r] *= linv;
    }

    {
        u16* pw = &P[(w * 16) * 200];
        #pragma unroll
        for (int r = 0; r < 4; ++r)
            #pragma unroll
            for (int f = 0; f < 12; ++f)
                pw[(g * 4 + r) * 200 + f * 16 + fr] = f2bu(p[f][r]);
    }
    __syncthreads();

    {
        const u16* vrow = vT + (size_t)(bb * kH + hh) * kDH * kS;
        for (int idx = tid; idx < 128 * 25; idx += 256) {
            int d = idx / 25, c = idx % 25;
            if (c < 24) {
                int s0k = kbase + c * 8;
                short8 v;
                if (s0k < 0) v = (short8){0, 0, 0, 0, 0, 0, 0, 0};
                else v = *(const short8*)(vrow + (size_t)d * kS + s0k);
                *(short8*)(&KV[d * 200 + c * 8]) = v;
            }
        }
    }
    __syncthreads();

    f32x4 oacc[8];
    #pragma unroll
    for (int f = 0; f < 8; ++f) oacc[f] = (f32x4){0.f, 0.f, 0.f, 0.f};
    const u16* pr = &P[(w * 16 + fr) * 200 + g * 8];
    #pragma unroll
    for (int s = 0; s < 6; ++s) {
        short8 afr = *(const short8*)(pr + s * 32);
        #pragma unroll
        for (int f = 0; f < 8; ++f) {
            short8 bfr = *(const short8*)(&KV[(f * 16 + fr) * 200 + s * 32 + g * 8]);
            oacc[f] = __builtin_amdgcn_mfma_f32_16x16x32_bf16(afr, bfr, oacc[f], 0, 0, 0);
        }
    }
    u16* orow = aob + ((size_t)(bb * kS + q0 + w * 16 + g * 4) * kD) + hh * kDH + fr;
    #pragma unroll
    for (int r = 0; r < 4; ++r)
        #pragma unroll
        for (int f = 0; f < 8; ++f)
            orow[(size_t)r * kD + f * 16] = f2bu(oacc[f][r]);
}

// ---------------------------------------------------------------------------
extern "C" void kernel_launch(void* const* d_in, const int* in_sizes, int n_in,
                              void* d_out, int out_size, void* d_ws, size_t ws_size,
                              hipStream_t stream)
{
    (void)in_sizes; (void)n_in; (void)out_size; (void)ws_size;

    const float* x          = (const float*)d_in[0];
    const float* rms_mix    = (const float*)d_in[1];
    const float* gate_w     = (const float*)d_in[2];
    const float* Wg         = (const float*)d_in[3];
    const float* bg         = (const float*)d_in[4];
    const float* Wv         = (const float*)d_in[5];
    const float* bv         = (const float*)d_in[6];
    const float* Wd         = (const float*)d_in[7];
    const float* bd         = (const float*)d_in[8];
    const float* rms_attn   = (const float*)d_in[9];
    const float* w_qkv      = (const float*)d_in[10];
    const float* w_attn_out = (const float*)d_in[11];
    const float* rms_ffn    = (const float*)d_in[12];
    const float* w_ffn_gate = (const float*)d_in[13];
    const float* w_ffn_up   = (const float*)d_in[14];
    const float* w_ffn_out  = (const float*)d_in[15];
    float* out = (float*)d_out;

    const size_t MD = (size_t)kM * kD;
    const size_t M1 = 1024ull * 1024;
    char* p = (char*)d_ws;
    auto take = [&](size_t n) { char* r = p; p += (n + 255) & ~(size_t)255; return r; };

    u16*   xnb    = (u16*)take(MD * 2);                     // 8.4 MB
    u16*   gvdall = (u16*)take((size_t)kM * kNE * 2);       // 100.7 MB: gvd | qkvb/hidA | hidB
    u16*   qkvb   = gvdall;
    u16*   hidA   = gvdall;
    u16*   hidB   = gvdall + (size_t)kM * kFFN;
    u16*   ehb    = (u16*)take(4 * MD * 2);                 // 33.6 MB: slots | aob+vT
    u16*   slot0  = ehb;
    u16*   slot1  = ehb + MD;
    u16*   aob    = ehb;
    u16*   vTb    = ehb + MD;
    u16*   wbuf   = (u16*)take(12ull * M1 * 2);             // 25.2 MB transposed weights
    float* pbias  = (float*)take((size_t)kNE * 4);
    float* sumA   = (float*)take(4ull * kNC * kB * kD * 4);
    float* sumX   = (float*)take(4ull * kNC * kB * kD * 4);
    float* carry  = (float*)take(4ull * kNC * kB * kD * 4);
    float* wts    = (float*)take((size_t)2 * kM * 4);
    int*   tidx   = (int*)take((size_t)2 * kM * 4);

    const dim3 blk(256);

    // ---- expert weight transposes (wbuf = BT[12288][1024]) + bias pack ----
    transp_k<<<dim3(32, 32, 4), blk, 0, stream>>>(Wg, wbuf, 1024, 1024,
                                                  (size_t)kD * kD, 3 * M1);
    transp_k<<<dim3(32, 32, 4), blk, 0, stream>>>(Wv, wbuf + M1, 1024, 1024,
                                                  (size_t)kD * kD, 3 * M1);
    transp_k<<<dim3(32, 32, 4), blk, 0, stream>>>(Wd, wbuf + 2 * M1, 1024, 1024,
                                                  (size_t)kD * kD, 3 * M1);
    biaspack_k<<<dim3(12, 4), blk, 0, stream>>>(bg, bv, bd, pbias);

    // ---- stage 1: rmsnorm + routing ----
    rmsnorm_k<<<kM, blk, 0, stream>>>(x, rms_mix, xnb);
    routing_k<<<kM, dim3(64), 0, stream>>>(x, rms_mix, gate_w, wts, tidx);

    // ---- experts: ONE batched GEMM (N=12288) + z-batched scans ----
    gemmA_k<true, false, false><<<dim3(kNE / 256, kM / 256), dim3(512), 0, stream>>>(
        xnb, wbuf, pbias, nullptr, gvdall, kNE, 1024);
    const int scan_blocks = kB * kD * kNC / 256;
    scan1_k<<<dim3(scan_blocks, 4), blk, 0, stream>>>(gvdall, sumA, sumX);
    scan2_k<<<dim3(kB * kD / 256, 4), blk, 0, stream>>>(sumA, sumX, carry);
    scan3_k<<<dim3(scan_blocks, 4), blk, 0, stream>>>(gvdall, carry, tidx, slot0, slot1);

    // ---- MoE mix + attn rmsnorm (fused) -> out (x1), xnb ----
    mixrms_k<<<kM, blk, 0, stream>>>(x, slot0, slot1, wts, rms_attn, out, xnb);

    // ---- attention ----
    transp_k<<<dim3(96, 32, 1), blk, 0, stream>>>(w_qkv, wbuf, 1024, 3072, 0, 0);
    gemmA_k<false, false, false><<<dim3(3072 / 256, kM / 256), dim3(512), 0, stream>>>(
        xnb, wbuf, nullptr, nullptr, qkvb, 3072, 1024);
    transpV_k<<<dim3(kS / 64, 2, kB * kH), blk, 0, stream>>>(qkvb, vTb);
    attn_mfma_k<<<dim3(kS / 64, kH, kB), blk, 0, stream>>>(qkvb, vTb, aob);
    transp_k<<<dim3(32, 32, 1), blk, 0, stream>>>(w_attn_out, wbuf + 3 * M1, 1024, 1024, 0, 0);
    gemmO_k<<<dim3(1024 / 64, kM / 256), dim3(512), 0, stream>>>(
        aob, wbuf + 3 * M1, out, out, 1024, 1024);

    // ---- FFN ----
    rmsnorm_k<<<kM, blk, 0, stream>>>(out, rms_ffn, xnb);
    transp_k<<<dim3(128, 32, 1), blk, 0, stream>>>(w_ffn_gate, wbuf + 4 * M1, 1024, 4096, 0, 0);
    transp_k<<<dim3(128, 32, 1), blk, 0, stream>>>(w_ffn_up, wbuf + 8 * M1, 1024, 4096, 0, 0);
    transp_k<<<dim3(32, 128, 1), blk, 0, stream>>>(w_ffn_out, wbuf, 4096, 1024, 0, 0);
    gemmA_k<false, true, false><<<dim3(kFFN / 256, kM / 256), dim3(512), 0, stream>>>(
        xnb, wbuf + 4 * M1, nullptr, nullptr, hidA, kFFN, 1024);
    gemmA_k<false, false, true><<<dim3(kFFN / 256, kM / 256), dim3(512), 0, stream>>>(
        xnb, wbuf + 8 * M1, nullptr, hidA, hidB, kFFN, 1024);
    gemmO_k<<<dim3(1024 / 64, kM / 256), dim3(512), 0, stream>>>(
        hidB, wbuf, out, out, 1024, 4096);
}

// Round 15
// 486.743 us; speedup vs baseline: 1.0614x; 1.0614x over previous
//
#include <hip/hip_runtime.h>
#include <hip/hip_bf16.h>
#include <math.h>

// Problem constants
constexpr int kB   = 2;
constexpr int kS   = 2048;
constexpr int kD   = 1024;
constexpr int kFFN = 4096;
constexpr int kM   = kB * kS;      // 4096 tokens
constexpr int kH   = 8;
constexpr int kDH  = 128;
constexpr int kNC  = 64;           // scan chunks
constexpr int kT   = kS / kNC;     // 32 steps per chunk
constexpr int kNE  = 12288;        // 4 experts x 3072 packed N

typedef unsigned short u16;
typedef __attribute__((ext_vector_type(8))) short short8;
typedef __attribute__((ext_vector_type(4))) float f32x4;

__device__ __forceinline__ float sigf(float x) { return 1.0f / (1.0f + __expf(-x)); }
__device__ __forceinline__ float bu2f(u16 u) { return __uint_as_float(((unsigned)u) << 16); }
__device__ __forceinline__ u16 f2bu(float f) {
    __hip_bfloat16 h = __float2bfloat16(f);
    return reinterpret_cast<u16&>(h);
}
__device__ __forceinline__ void async16(const void* g, void* l) {
    __builtin_amdgcn_global_load_lds((const __attribute__((address_space(1))) void*)g,
                                     (__attribute__((address_space(3))) void*)l, 16, 0, 0);
}
// bijective XCD swizzle (m204)
__device__ __forceinline__ int xcd_swz(int orig, int nwg) {
    const int xcd = orig & 7;
    const int q8 = nwg >> 3, r8 = nwg & 7;
    return (xcd < r8 ? xcd * (q8 + 1) : r8 * (q8 + 1) + (xcd - r8) * q8) + (orig >> 3);
}

// ---------------- RMSNorm: f32 in, bf16 out ---------------------------------
__global__ __launch_bounds__(256) void rmsnorm_k(const float* __restrict__ x,
                                                 const float* __restrict__ w,
                                                 u16* __restrict__ o)
{
    __shared__ float red[4];
    const int row = blockIdx.x;
    const int t = threadIdx.x;
    float4 v = ((const float4*)(x + (size_t)row * kD))[t];
    float ss = v.x*v.x + v.y*v.y + v.z*v.z + v.w*v.w;
    #pragma unroll
    for (int m = 32; m; m >>= 1) ss += __shfl_xor(ss, m);
    if ((t & 63) == 0) red[t >> 6] = ss;
    __syncthreads();
    float tot = red[0] + red[1] + red[2] + red[3];
    float r = rsqrtf(tot * (1.0f / (float)kD) + 1e-6f);
    float4 wv = ((const float4*)w)[t];
    ushort4 u;
    u.x = f2bu(v.x * r * wv.x); u.y = f2bu(v.y * r * wv.y);
    u.z = f2bu(v.z * r * wv.z); u.w = f2bu(v.w * r * wv.w);
    ((ushort4*)(o + (size_t)row * kD))[t] = u;
}

// ---------------- Routing: pure f32 from x (top-k must not see bf16) --------
__global__ __launch_bounds__(64) void routing_k(const float* __restrict__ x,
                                                const float* __restrict__ wmix,
                                                const float* __restrict__ gw,
                                                float* __restrict__ wts,
                                                int* __restrict__ idx)
{
    const int row = blockIdx.x;
    const int lane = threadIdx.x;
    const float* xr = x + (size_t)row * kD;
    float ss = 0.0f;
    for (int d = lane; d < kD; d += 64) { float v = xr[d]; ss = fmaf(v, v, ss); }
    #pragma unroll
    for (int m = 32; m; m >>= 1) ss += __shfl_xor(ss, m);
    float r = rsqrtf(ss * (1.0f / (float)kD) + 1e-6f);

    float a0 = 0, a1 = 0, a2 = 0, a3 = 0;
    for (int d = lane; d < kD; d += 64) {
        float xv = xr[d] * wmix[d];
        float4 g = ((const float4*)gw)[d];
        a0 = fmaf(xv, g.x, a0);
        a1 = fmaf(xv, g.y, a1);
        a2 = fmaf(xv, g.z, a2);
        a3 = fmaf(xv, g.w, a3);
    }
    #pragma unroll
    for (int m = 32; m; m >>= 1) {
        a0 += __shfl_xor(a0, m);
        a1 += __shfl_xor(a1, m);
        a2 += __shfl_xor(a2, m);
        a3 += __shfl_xor(a3, m);
    }
    if (lane == 0) {
        float a[4] = {a0, a1, a2, a3};
        int i0 = 0; float v0 = a[0];
        #pragma unroll
        for (int e = 1; e < 4; ++e) if (a[e] > v0) { v0 = a[e]; i0 = e; }
        int i1 = -1; float v1 = -INFINITY;
        #pragma unroll
        for (int e = 0; e < 4; ++e) if (e != i0 && a[e] > v1) { v1 = a[e]; i1 = e; }
        float e1 = __expf(r * (v1 - v0));
        float dn = 1.0f + e1;
        wts[row * 2 + 0] = 1.0f / dn;
        wts[row * 2 + 1] = e1 / dn;
        idx[row * 2 + 0] = i0;
        idx[row * 2 + 1] = i1;
    }
}

// ---------------- Transpose-convert: f32 [rows][cols] -> bf16 [cols][rows] --
__global__ __launch_bounds__(256) void transp_k(const float* __restrict__ src,
                                                u16* __restrict__ dst,
                                                int rows, int cols,
                                                size_t sstride, size_t dstride)
{
    __shared__ float t[32][33];
    const float* s = src + blockIdx.z * sstride;
    u16* d = dst + blockIdx.z * dstride;
    const int c0 = blockIdx.x * 32, r0 = blockIdx.y * 32;
    const int tc = threadIdx.x & 31, tr4 = (threadIdx.x >> 5) * 4;
    #pragma unroll
    for (int i = 0; i < 4; ++i)
        t[tr4 + i][tc] = s[(size_t)(r0 + tr4 + i) * cols + c0 + tc];
    __syncthreads();
    #pragma unroll
    for (int i = 0; i < 4; ++i) {
        int cc = tr4 + i;
        d[(size_t)(c0 + cc) * rows + r0 + tc] = f2bu(t[tc][cc]);
    }
}

// ---------------- Bias pack: [12288] = e-major (bg|bv|bd) -------------------
__global__ __launch_bounds__(256) void biaspack_k(const float* __restrict__ bg,
                                                  const float* __restrict__ bv,
                                                  const float* __restrict__ bd,
                                                  float* __restrict__ pb)
{
    int e = blockIdx.y;
    int r = blockIdx.x * 256 + threadIdx.x;   // 0..3071
    const float* src = (r < 1024) ? bg : (r < 2048) ? bv : bd;
    pb[e * 3072 + r] = src[e * 1024 + (r & 1023)];
}

// ---------------- gemmA: BM=256 BN=256 BK=64, 8 waves (2Mx4N), per-wave 128x64
// R12-verified: 2-buffer double-buffer; __syncthreads per K-tile (issue-early
// loads land under MFMA; wave-level overlap hides the drain). Zero-conflict
// swizzle. M-fastest XCD mapping -> B panel L2-resident.
template<bool BIAS, bool SILU, bool MUL>
__global__ __launch_bounds__(512, 2) void gemmA_k(
    const u16* __restrict__ A, const u16* __restrict__ BT,
    const float* __restrict__ bias, const u16* __restrict__ mulsrc,
    u16* __restrict__ Cout, int N, int K)
{
    __shared__ __align__(16) u16 lds[2][32768];   // per stage: A[256][64] | B[256][64]
    const int tid = threadIdx.x;
    const int l = tid & 63;
    const int w = tid >> 6;                 // 0..7
    const int wr = w >> 2, wc = w & 3;      // 2M x 4N
    const int fr = l & 15, g = l >> 4;

    const int my = gridDim.y;               // M blocks
    const int wg = xcd_swz(blockIdx.y * gridDim.x + blockIdx.x, gridDim.x * my);
    const int bm = (wg % my) * 256, bn = (wg / my) * 256;   // M-fastest

    const int srow = l >> 3;
    const int scol = (l & 7) ^ srow;        // pre-swizzled source col-chunk
    const u16* gA = A  + (size_t)(bm + srow) * K + scol * 8;
    const u16* gB = BT + (size_t)(bn + srow) * K + scol * 8;

    auto STAGE = [&](int kt, int sb) {
        u16* dst = lds[sb] + l * 8;
        const int k0 = kt * 64;
        #pragma unroll
        for (int i = 0; i < 4; ++i) {
            int chunk = w * 4 + i;
            async16(gA + (size_t)chunk * 8 * K + k0, dst + chunk * 512);
            async16(gB + (size_t)chunk * 8 * K + k0, dst + 16384 + chunk * 512);
        }
    };

    f32x4 acc[8][4];
    #pragma unroll
    for (int m = 0; m < 8; ++m)
        #pragma unroll
        for (int n = 0; n < 4; ++n) acc[m][n] = (f32x4){0.f, 0.f, 0.f, 0.f};

    STAGE(0, 0);
    __syncthreads();
    const int nt = K >> 6;
    for (int t = 0; t < nt; ++t) {
        const int cb = t & 1;
        if (t + 1 < nt) STAGE(t + 1, cb ^ 1);   // issue-early; lands under MFMA
        const u16* bA = lds[cb];
        const u16* bB = lds[cb] + 16384;
        #pragma unroll
        for (int ks = 0; ks < 2; ++ks) {
            const int xo = ((ks * 4 + g) ^ (fr & 7)) * 8;
            short8 b[4];
            #pragma unroll
            for (int n = 0; n < 4; ++n)
                b[n] = *(const short8*)(bB + (wc * 64 + n * 16 + fr) * 64 + xo);
            #pragma unroll
            for (int m = 0; m < 8; ++m) {
                short8 a = *(const short8*)(bA + (wr * 128 + m * 16 + fr) * 64 + xo);
                #pragma unroll
                for (int n = 0; n < 4; ++n)
                    acc[m][n] = __builtin_amdgcn_mfma_f32_16x16x32_bf16(a, b[n], acc[m][n], 0, 0, 0);
            }
        }
        __syncthreads();   // drains t+1 loads; guards buf reuse
    }

    const int orow0 = bm + wr * 128 + g * 4;
    const int ocol0 = bn + wc * 64 + fr;
    float bi[4];
    if constexpr (BIAS) {
        #pragma unroll
        for (int n = 0; n < 4; ++n) bi[n] = bias[ocol0 + n * 16];
    }
    #pragma unroll
    for (int m = 0; m < 8; ++m) {
        #pragma unroll
        for (int r = 0; r < 4; ++r) {
            const size_t ro = (size_t)(orow0 + m * 16 + r) * N;
            #pragma unroll
            for (int n = 0; n < 4; ++n) {
                const size_t off = ro + ocol0 + n * 16;
                float v = acc[m][n][r];
                if constexpr (BIAS) v += bi[n];
                if constexpr (SILU) v = v * sigf(v);
                if constexpr (MUL)  v *= bu2f(mulsrc[off]);
                Cout[off] = f2bu(v);
            }
        }
    }
}

// ---------------- gemmGU: fused FFN gate+up dual GEMM -----------------------
// BM=256, BN=128 (output cols), BK=64, 8 waves (2Mx4N), per-wave 128x32 of
// BOTH gate and up. A-frags shared by both MFMA sets (reads/MFMA = 0.375,
// same as gemmA); acc_g[8][2]+acc_u[8][2] = same 128-reg budget as gemmA.
// Epilogue: hidB = bf16(silu(g)*u) in f32 registers — hidA eliminated.
__global__ __launch_bounds__(512, 2) void gemmGU_k(
    const u16* __restrict__ A, const u16* __restrict__ GT,
    const u16* __restrict__ UT, u16* __restrict__ Cout, int N, int K)
{
    __shared__ __align__(16) u16 ldsA[2][16384];   // A[256][64]
    __shared__ __align__(16) u16 ldsG[2][8192];    // gate[128][64]
    __shared__ __align__(16) u16 ldsU[2][8192];    // up  [128][64]
    const int tid = threadIdx.x;
    const int l = tid & 63;
    const int w = tid >> 6;                 // 0..7
    const int wr = w >> 2, wc = w & 3;      // 2M x 4N (N in 32-col slots)
    const int fr = l & 15, g = l >> 4;

    const int my = gridDim.y;
    const int wg = xcd_swz(blockIdx.y * gridDim.x + blockIdx.x, gridDim.x * my);
    const int bm = (wg % my) * 256, bn = (wg / my) * 128;   // M-fastest

    const int srow = l >> 3;
    const int scol = (l & 7) ^ srow;
    const u16* gA = A  + (size_t)(bm + srow) * K + scol * 8;
    const u16* gG = GT + (size_t)(bn + srow) * K + scol * 8;
    const u16* gU = UT + (size_t)(bn + srow) * K + scol * 8;

    auto STAGE = [&](int kt, int sb) {      // 8 async16/thread (A4 + G2 + U2)
        const int k0 = kt * 64;
        u16* dA = ldsA[sb] + l * 8;
        #pragma unroll
        for (int i = 0; i < 4; ++i) {
            int chunk = w * 4 + i;
            async16(gA + (size_t)chunk * 8 * K + k0, dA + chunk * 512);
        }
        u16* dG = ldsG[sb] + l * 8;
        u16* dU = ldsU[sb] + l * 8;
        #pragma unroll
        for (int i = 0; i < 2; ++i) {
            int chunk = w * 2 + i;          // 16 chunks of 8 rows = 128 rows
            async16(gG + (size_t)chunk * 8 * K + k0, dG + chunk * 512);
            async16(gU + (size_t)chunk * 8 * K + k0, dU + chunk * 512);
        }
    };

    f32x4 accg[8][2], accu[8][2];
    #pragma unroll
    for (int m = 0; m < 8; ++m)
        #pragma unroll
        for (int n = 0; n < 2; ++n) {
            accg[m][n] = (f32x4){0.f, 0.f, 0.f, 0.f};
            accu[m][n] = (f32x4){0.f, 0.f, 0.f, 0.f};
        }

    STAGE(0, 0);
    __syncthreads();
    const int nt = K >> 6;
    for (int t = 0; t < nt; ++t) {
        const int cb = t & 1;
        if (t + 1 < nt) STAGE(t + 1, cb ^ 1);
        const u16* bA = ldsA[cb];
        const u16* bG = ldsG[cb];
        const u16* bU = ldsU[cb];
        #pragma unroll
        for (int ks = 0; ks < 2; ++ks) {
            const int xo = ((ks * 4 + g) ^ (fr & 7)) * 8;
            short8 vg[2], vu[2];
            #pragma unroll
            for (int n = 0; n < 2; ++n) {
                vg[n] = *(const short8*)(bG + (wc * 32 + n * 16 + fr) * 64 + xo);
                vu[n] = *(const short8*)(bU + (wc * 32 + n * 16 + fr) * 64 + xo);
            }
            #pragma unroll
            for (int m = 0; m < 8; ++m) {
                short8 a = *(const short8*)(bA + (wr * 128 + m * 16 + fr) * 64 + xo);
                #pragma unroll
                for (int n = 0; n < 2; ++n) {
                    accg[m][n] = __builtin_amdgcn_mfma_f32_16x16x32_bf16(a, vg[n], accg[m][n], 0, 0, 0);
                    accu[m][n] = __builtin_amdgcn_mfma_f32_16x16x32_bf16(a, vu[n], accu[m][n], 0, 0, 0);
                }
            }
        }
        __syncthreads();
    }

    const int orow0 = bm + wr * 128 + g * 4;
    const int ocol0 = bn + wc * 32 + fr;
    #pragma unroll
    for (int m = 0; m < 8; ++m) {
        #pragma unroll
        for (int r = 0; r < 4; ++r) {
            const size_t ro = (size_t)(orow0 + m * 16 + r) * N;
            #pragma unroll
            for (int n = 0; n < 2; ++n) {
                float gv = accg[m][n][r];
                float uv = accu[m][n][r];
                Cout[ro + ocol0 + n * 16] = f2bu(gv * sigf(gv) * uv);
            }
        }
    }
}

// ---------------- gemmO: BM=256 BN=64 BK=64, 8 waves (4Mx2N), 2-stage --------
// Out-projection: f32 residual add, f32 out. LDS 80KB -> 2 blocks/CU.
__global__ __launch_bounds__(512, 2) void gemmO_k(
    const u16* __restrict__ A, const u16* __restrict__ BT,
    const float* __restrict__ res, float* __restrict__ Cout,
    int N, int K)
{
    __shared__ __align__(16) u16 lds[2][20480];   // per stage: A[256][64] | B[64][64]
    const int tid = threadIdx.x;
    const int l = tid & 63;
    const int w = tid >> 6;                 // 0..7
    const int wr = w >> 1, wc = w & 1;      // 4M x 2N; per-wave 64x32
    const int fr = l & 15, g = l >> 4;

    const int my = gridDim.y;
    const int wg = xcd_swz(blockIdx.y * gridDim.x + blockIdx.x, gridDim.x * my);
    const int bm = (wg % my) * 256, bn = (wg / my) * 64;    // M-fastest

    const int srow = l >> 3;
    const int scol = (l & 7) ^ srow;
    const u16* gA = A  + (size_t)(bm + srow) * K + scol * 8;
    const u16* gB = BT + (size_t)(bn + srow) * K + scol * 8;

    auto STAGE = [&](int kt, int sb) {
        u16* dst = lds[sb] + l * 8;
        const int k0 = kt * 64;
        #pragma unroll
        for (int i = 0; i < 4; ++i) {       // A: 32 chunks / 8 waves
            int chunk = w * 4 + i;
            async16(gA + (size_t)chunk * 8 * K + k0, dst + chunk * 512);
        }
        // B: 8 chunks / 8 waves (1 each)
        async16(gB + (size_t)w * 8 * K + k0, dst + 16384 + w * 512);
    };

    f32x4 acc[4][2];
    #pragma unroll
    for (int m = 0; m < 4; ++m)
        #pragma unroll
        for (int n = 0; n < 2; ++n) acc[m][n] = (f32x4){0.f, 0.f, 0.f, 0.f};

    STAGE(0, 0);
    __syncthreads();
    const int nt = K >> 6;
    for (int t = 0; t < nt; ++t) {
        const int cb = t & 1;
        if (t + 1 < nt) STAGE(t + 1, cb ^ 1);
        const u16* bA = lds[cb];
        const u16* bB = lds[cb] + 16384;
        #pragma unroll
        for (int ks = 0; ks < 2; ++ks) {
            const int xo = ((ks * 4 + g) ^ (fr & 7)) * 8;
            short8 a[4], b[2];
            #pragma unroll
            for (int m = 0; m < 4; ++m)
                a[m] = *(const short8*)(bA + (wr * 64 + m * 16 + fr) * 64 + xo);
            #pragma unroll
            for (int n = 0; n < 2; ++n)
                b[n] = *(const short8*)(bB + (wc * 32 + n * 16 + fr) * 64 + xo);
            #pragma unroll
            for (int m = 0; m < 4; ++m)
                #pragma unroll
                for (int n = 0; n < 2; ++n)
                    acc[m][n] = __builtin_amdgcn_mfma_f32_16x16x32_bf16(a[m], b[n], acc[m][n], 0, 0, 0);
        }
        __syncthreads();
    }

    const int orow0 = bm + wr * 64 + g * 4;
    const int ocol0 = bn + wc * 32 + fr;
    #pragma unroll
    for (int m = 0; m < 4; ++m) {
        #pragma unroll
        for (int r = 0; r < 4; ++r) {
            const size_t ro = (size_t)(orow0 + m * 16 + r) * N;
            #pragma unroll
            for (int n = 0; n < 2; ++n) {
                const size_t off = ro + ocol0 + n * 16;
                Cout[off] = acc[m][n][r] + res[off];
            }
        }
    }
}

// ---------------- minGRU chunked scan over gvdall [M][12288] ----------------
__global__ __launch_bounds__(256) void scan1_k(const u16* __restrict__ gvdall,
                                               float* __restrict__ sumA,
                                               float* __restrict__ sumX)
{
    const int e = blockIdx.y;
    int i = blockIdx.x * 256 + threadIdx.x;      // [0, kB*kNC*kD)
    int d = i & (kD - 1);
    int c = (i >> 10) & (kNC - 1);
    int b = i >> 16;
    const u16* gvd = gvdall + e * 3072;
    size_t base = ((size_t)b * kS + c * kT) * kNE + d;
    float A = 1.0f, X = 0.0f;
    for (int t = 0; t < kT; ++t) {
        size_t ix = base + (size_t)t * kNE;
        float xs = sigf(bu2f(gvd[ix])) * tanhf(bu2f(gvd[ix + 1024]));
        float a  = 0.001f + 0.998f * sigf(bu2f(gvd[ix + 2048]));
        A *= a;
        X = fmaf(a, X, xs);
    }
    size_t si = ((size_t)(e * kNC + c) * kB + b) * kD + d;
    sumA[si] = A;
    sumX[si] = X;
}

__global__ __launch_bounds__(256) void scan2_k(const float* __restrict__ sumA,
                                               const float* __restrict__ sumX,
                                               float* __restrict__ carry)
{
    const int e = blockIdx.y;
    int bd = blockIdx.x * 256 + threadIdx.x;     // [0, kB*kD)
    float h = 0.0f;
    for (int c = 0; c < kNC; ++c) {
        size_t si = ((size_t)(e * kNC + c)) * (kB * kD) + bd;
        carry[si] = h;
        h = fmaf(sumA[si], h, sumX[si]);
    }
}

// scan3: write h ONLY for the token's 2 selected experts (slot buffers)
__global__ __launch_bounds__(256) void scan3_k(const u16* __restrict__ gvdall,
                                               const float* __restrict__ carry,
                                               const int* __restrict__ tidx,
                                               u16* __restrict__ slot0,
                                               u16* __restrict__ slot1)
{
    const int e = blockIdx.y;
    int i = blockIdx.x * 256 + threadIdx.x;
    int d = i & (kD - 1);
    int c = (i >> 10) & (kNC - 1);
    int b = i >> 16;
    const u16* gvd = gvdall + e * 3072;
    size_t base = ((size_t)b * kS + c * kT) * kNE + d;
    float h = carry[((size_t)(e * kNC + c) * kB + b) * kD + d];
    const int tok0 = b * kS + c * kT;
    for (int t = 0; t < kT; ++t) {
        size_t ix = base + (size_t)t * kNE;
        float xs = sigf(bu2f(gvd[ix])) * tanhf(bu2f(gvd[ix + 1024]));
        float a  = 0.001f + 0.998f * sigf(bu2f(gvd[ix + 2048]));
        h = fmaf(a, h, xs);
        const int tok = tok0 + t;
        const size_t o = (size_t)tok * kD + d;
        if (e == tidx[tok * 2])          slot0[o] = f2bu(h);
        else if (e == tidx[tok * 2 + 1]) slot1[o] = f2bu(h);
    }
}

// ---------------- Fused MoE mix + attn RMSNorm -------------------------------
__global__ __launch_bounds__(256) void mixrms_k(const float* __restrict__ x,
                                                const u16* __restrict__ slot0,
                                                const u16* __restrict__ slot1,
                                                const float* __restrict__ wts,
                                                const float* __restrict__ w,
                                                float* __restrict__ xo,
                                                u16* __restrict__ xn)
{
    __shared__ float red[4];
    const int row = blockIdx.x;
    const int t = threadIdx.x;
    const size_t i = (size_t)row * 256 + t;     // float4 index
    float w0 = wts[row * 2 + 0], w1 = wts[row * 2 + 1];
    float4 xv = ((const float4*)x)[i];
    ushort4 h0 = ((const ushort4*)slot0)[i];
    ushort4 h1 = ((const ushort4*)slot1)[i];
    float4 o;
    o.x = xv.x + w0 * bu2f(h0.x) + w1 * bu2f(h1.x);
    o.y = xv.y + w0 * bu2f(h0.y) + w1 * bu2f(h1.y);
    o.z = xv.z + w0 * bu2f(h0.z) + w1 * bu2f(h1.z);
    o.w = xv.w + w0 * bu2f(h0.w) + w1 * bu2f(h1.w);
    ((float4*)xo)[i] = o;

    float ss = o.x*o.x + o.y*o.y + o.z*o.z + o.w*o.w;
    #pragma unroll
    for (int m = 32; m; m >>= 1) ss += __shfl_xor(ss, m);
    if ((t & 63) == 0) red[t >> 6] = ss;
    __syncthreads();
    float tot = red[0] + red[1] + red[2] + red[3];
    float r = rsqrtf(tot * (1.0f / (float)kD) + 1e-6f);
    float4 wv = ((const float4*)w)[t];
    ushort4 u;
    u.x = f2bu(o.x * r * wv.x); u.y = f2bu(o.y * r * wv.y);
    u.z = f2bu(o.z * r * wv.z); u.w = f2bu(o.w * r * wv.w);
    ((ushort4*)(xn + (size_t)row * kD))[t] = u;
}

// ---------------- V transpose: qkvb V-part -> vT [b*H+h][128 d][2048 s] -----
__global__ __launch_bounds__(256) void transpV_k(const u16* __restrict__ qkvb,
                                                 u16* __restrict__ vT)
{
    __shared__ u16 t[64][68];
    const int tid = threadIdx.x;
    const int s0 = blockIdx.x * 64;
    const int d0 = blockIdx.y * 64;
    const int bh = blockIdx.z;
    const int bb = bh >> 3, hh = bh & 7;
    const u16* src = qkvb + (size_t)(bb * kS + s0) * 3072 + 2048 + hh * kDH + d0;
    for (int idx = tid; idx < 64 * 16; idx += 256) {
        int sl = idx >> 4, c4 = (idx & 15) * 4;
        *(ushort4*)&t[sl][c4] = *(const ushort4*)(src + (size_t)sl * 3072 + c4);
    }
    __syncthreads();
    u16* dst = vT + ((size_t)bh * kDH + d0) * kS + s0;
    for (int idx = tid; idx < 64 * 16; idx += 256) {
        int dl = idx >> 4, s4 = (idx & 15) * 4;
        ushort4 v;
        v.x = t[s4 + 0][dl]; v.y = t[s4 + 1][dl];
        v.z = t[s4 + 2][dl]; v.w = t[s4 + 3][dl];
        *(ushort4*)(dst + (size_t)dl * kS + s4) = v;
    }
}

// ---------------- MFMA sliding-window attention ------------------------------
__global__ __launch_bounds__(256) void attn_mfma_k(const u16* __restrict__ qkvb,
                                                   const u16* __restrict__ vT,
                                                   u16* __restrict__ aob)
{
    __shared__ __align__(16) u16 KV[26112];      // K: [192][136] | VT: [128][200]
    __shared__ __align__(16) u16 P[4 * 16 * 200];

    const int tid = threadIdx.x;
    const int lane = tid & 63;
    const int w = tid >> 6;
    const int fr = lane & 15, g = lane >> 4;
    const int q0 = blockIdx.x * 64;
    const int hh = blockIdx.y;
    const int bb = blockIdx.z;
    const int kbase = q0 - 128;
    const float scale = 0.08838834764831845f;    // 1/sqrt(128)

    const u16* qkv_b = qkvb + (size_t)bb * kS * 3072 + hh * kDH;

    for (int idx = tid; idx < 192 * 16; idx += 256) {
        int k = idx >> 4, c = idx & 15;
        int kg = kbase + k; if (kg < 0) kg = 0;
        short8 v = *(const short8*)(qkv_b + (size_t)kg * 3072 + 1024 + c * 8);
        *(short8*)(&KV[k * 136 + c * 8]) = v;
    }
    short8 qf[4];
    {
        const u16* qrow = qkv_b + (size_t)(q0 + w * 16 + fr) * 3072 + g * 8;
        #pragma unroll
        for (int s = 0; s < 4; ++s) qf[s] = *(const short8*)(qrow + s * 32);
    }
    __syncthreads();

    f32x4 sacc[12];
    #pragma unroll
    for (int f = 0; f < 12; ++f) sacc[f] = (f32x4){0.f, 0.f, 0.f, 0.f};
    #pragma unroll
    for (int s = 0; s < 4; ++s) {
        #pragma unroll
        for (int f = 0; f < 12; ++f) {
            short8 bfr = *(const short8*)(&KV[(f * 16 + fr) * 136 + s * 32 + g * 8]);
            sacc[f] = __builtin_amdgcn_mfma_f32_16x16x32_bf16(qf[s], bfr, sacc[f], 0, 0, 0);
        }
    }

    float p[12][4];
    #pragma unroll
    for (int r = 0; r < 4; ++r) {
        const int ql = w * 16 + g * 4 + r;
        int kmin = 128 - q0; if (kmin < ql + 1) kmin = ql + 1;
        const int kmax = ql + 128;
        float mx = -1e30f;
        #pragma unroll
        for (int f = 0; f < 12; ++f) {
            int kl = f * 16 + fr;
            float sv = (kl >= kmin && kl <= kmax) ? sacc[f][r] * scale : -1e30f;
            p[f][r] = sv;
            mx = fmaxf(mx, sv);
        }
        mx = fmaxf(mx, __shfl_xor(mx, 1));
        mx = fmaxf(mx, __shfl_xor(mx, 2));
        mx = fmaxf(mx, __shfl_xor(mx, 4));
        mx = fmaxf(mx, __shfl_xor(mx, 8));
        float l = 0.f;
        #pragma unroll
        for (int f = 0; f < 12; ++f) { float e = __expf(p[f][r] - mx); p[f][r] = e; l += e; }
        l += __shfl_xor(l, 1);
        l += __shfl_xor(l, 2);
        l += __shfl_xor(l, 4);
        l += __shfl_xor(l, 8);
        float linv = 1.0f / l;
        #pragma unroll
        for (int f = 0; f < 12; ++f) p[f][r] *= linv;
    }

    {
        u16* pw = &P[(w * 16) * 200];
        #pragma unroll
        for (int r = 0; r < 4; ++r)
            #pragma unroll
            for (int f = 0; f < 12; ++f)
                pw[(g * 4 + r) * 200 + f * 16 + fr] = f2bu(p[f][r]);
    }
    __syncthreads();

    {
        const u16* vrow = vT + (size_t)(bb * kH + hh) * kDH * kS;
        for (int idx = tid; idx < 128 * 25; idx += 256) {
            int d = idx / 25, c = idx % 25;
            if (c < 24) {
                int s0k = kbase + c * 8;
                short8 v;
                if (s0k < 0) v = (short8){0, 0, 0, 0, 0, 0, 0, 0};
                else v = *(const short8*)(vrow + (size_t)d * kS + s0k);
                *(short8*)(&KV[d * 200 + c * 8]) = v;
            }
        }
    }
    __syncthreads();

    f32x4 oacc[8];
    #pragma unroll
    for (int f = 0; f < 8; ++f) oacc[f] = (f32x4){0.f, 0.f, 0.f, 0.f};
    const u16* pr = &P[(w * 16 + fr) * 200 + g * 8];
    #pragma unroll
    for (int s = 0; s < 6; ++s) {
        short8 afr = *(const short8*)(pr + s * 32);
        #pragma unroll
        for (int f = 0; f < 8; ++f) {
            short8 bfr = *(const short8*)(&KV[(f * 16 + fr) * 200 + s * 32 + g * 8]);
            oacc[f] = __builtin_amdgcn_mfma_f32_16x16x32_bf16(afr, bfr, oacc[f], 0, 0, 0);
        }
    }
    u16* orow = aob + ((size_t)(bb * kS + q0 + w * 16 + g * 4) * kD) + hh * kDH + fr;
    #pragma unroll
    for (int r = 0; r < 4; ++r)
        #pragma unroll
        for (int f = 0; f < 8; ++f)
            orow[(size_t)r * kD + f * 16] = f2bu(oacc[f][r]);
}

// ---------------------------------------------------------------------------
extern "C" void kernel_launch(void* const* d_in, const int* in_sizes, int n_in,
                              void* d_out, int out_size, void* d_ws, size_t ws_size,
                              hipStream_t stream)
{
    (void)in_sizes; (void)n_in; (void)out_size; (void)ws_size;

    const float* x          = (const float*)d_in[0];
    const float* rms_mix    = (const float*)d_in[1];
    const float* gate_w     = (const float*)d_in[2];
    const float* Wg         = (const float*)d_in[3];
    const float* bg         = (const float*)d_in[4];
    const float* Wv         = (const float*)d_in[5];
    const float* bv         = (const float*)d_in[6];
    const float* Wd         = (const float*)d_in[7];
    const float* bd         = (const float*)d_in[8];
    const float* rms_attn   = (const float*)d_in[9];
    const float* w_qkv      = (const float*)d_in[10];
    const float* w_attn_out = (const float*)d_in[11];
    const float* rms_ffn    = (const float*)d_in[12];
    const float* w_ffn_gate = (const float*)d_in[13];
    const float* w_ffn_up   = (const float*)d_in[14];
    const float* w_ffn_out  = (const float*)d_in[15];
    float* out = (float*)d_out;

    const size_t MD = (size_t)kM * kD;
    const size_t M1 = 1024ull * 1024;
    char* p = (char*)d_ws;
    auto take = [&](size_t n) { char* r = p; p += (n + 255) & ~(size_t)255; return r; };

    u16*   xnb    = (u16*)take(MD * 2);                     // 8.4 MB
    u16*   gvdall = (u16*)take((size_t)kM * kNE * 2);       // 100.7 MB: gvd | qkvb | hidB
    u16*   qkvb   = gvdall;
    u16*   hidB   = gvdall + (size_t)kM * kFFN;
    u16*   ehb    = (u16*)take(4 * MD * 2);                 // 33.6 MB: slots | aob+vT
    u16*   slot0  = ehb;
    u16*   slot1  = ehb + MD;
    u16*   aob    = ehb;
    u16*   vTb    = ehb + MD;
    u16*   wbuf   = (u16*)take(12ull * M1 * 2);             // 25.2 MB transposed weights
    float* pbias  = (float*)take((size_t)kNE * 4);
    float* sumA   = (float*)take(4ull * kNC * kB * kD * 4);
    float* sumX   = (float*)take(4ull * kNC * kB * kD * 4);
    float* carry  = (float*)take(4ull * kNC * kB * kD * 4);
    float* wts    = (float*)take((size_t)2 * kM * 4);
    int*   tidx   = (int*)take((size_t)2 * kM * 4);

    const dim3 blk(256);

    // ---- expert weight transposes (wbuf = BT[12288][1024]) + bias pack ----
    transp_k<<<dim3(32, 32, 4), blk, 0, stream>>>(Wg, wbuf, 1024, 1024,
                                                  (size_t)kD * kD, 3 * M1);
    transp_k<<<dim3(32, 32, 4), blk, 0, stream>>>(Wv, wbuf + M1, 1024, 1024,
                                                  (size_t)kD * kD, 3 * M1);
    transp_k<<<dim3(32, 32, 4), blk, 0, stream>>>(Wd, wbuf + 2 * M1, 1024, 1024,
                                                  (size_t)kD * kD, 3 * M1);
    biaspack_k<<<dim3(12, 4), blk, 0, stream>>>(bg, bv, bd, pbias);

    // ---- stage 1: rmsnorm + routing ----
    rmsnorm_k<<<kM, blk, 0, stream>>>(x, rms_mix, xnb);
    routing_k<<<kM, dim3(64), 0, stream>>>(x, rms_mix, gate_w, wts, tidx);

    // ---- experts: ONE batched GEMM (N=12288) + z-batched scans ----
    gemmA_k<true, false, false><<<dim3(kNE / 256, kM / 256), dim3(512), 0, stream>>>(
        xnb, wbuf, pbias, nullptr, gvdall, kNE, 1024);
    const int scan_blocks = kB * kD * kNC / 256;
    scan1_k<<<dim3(scan_blocks, 4), blk, 0, stream>>>(gvdall, sumA, sumX);
    scan2_k<<<dim3(kB * kD / 256, 4), blk, 0, stream>>>(sumA, sumX, carry);
    scan3_k<<<dim3(scan_blocks, 4), blk, 0, stream>>>(gvdall, carry, tidx, slot0, slot1);

    // ---- MoE mix + attn rmsnorm (fused) -> out (x1), xnb ----
    mixrms_k<<<kM, blk, 0, stream>>>(x, slot0, slot1, wts, rms_attn, out, xnb);

    // ---- attention ----
    transp_k<<<dim3(96, 32, 1), blk, 0, stream>>>(w_qkv, wbuf, 1024, 3072, 0, 0);
    gemmA_k<false, false, false><<<dim3(3072 / 256, kM / 256), dim3(512), 0, stream>>>(
        xnb, wbuf, nullptr, nullptr, qkvb, 3072, 1024);
    transpV_k<<<dim3(kS / 64, 2, kB * kH), blk, 0, stream>>>(qkvb, vTb);
    attn_mfma_k<<<dim3(kS / 64, kH, kB), blk, 0, stream>>>(qkvb, vTb, aob);
    transp_k<<<dim3(32, 32, 1), blk, 0, stream>>>(w_attn_out, wbuf + 3 * M1, 1024, 1024, 0, 0);
    gemmO_k<<<dim3(1024 / 64, kM / 256), dim3(512), 0, stream>>>(
        aob, wbuf + 3 * M1, out, out, 1024, 1024);

    // ---- FFN: fused gate+up (dual), then out proj ----
    rmsnorm_k<<<kM, blk, 0, stream>>>(out, rms_ffn, xnb);
    transp_k<<<dim3(128, 32, 1), blk, 0, stream>>>(w_ffn_gate, wbuf + 4 * M1, 1024, 4096, 0, 0);
    transp_k<<<dim3(128, 32, 1), blk, 0, stream>>>(w_ffn_up, wbuf + 8 * M1, 1024, 4096, 0, 0);
    transp_k<<<dim3(32, 128, 1), blk, 0, stream>>>(w_ffn_out, wbuf, 4096, 1024, 0, 0);
    gemmGU_k<<<dim3(kFFN / 128, kM / 256), dim3(512), 0, stream>>>(
        xnb, wbuf + 4 * M1, wbuf + 8 * M1, hidB, kFFN, 1024);
    gemmO_k<<<dim3(1024 / 64, kM / 256), dim3(512), 0, stream>>>(
        hidB, wbuf, out, out, 1024, 4096);
}

// Round 16
// 470.718 us; speedup vs baseline: 1.0975x; 1.0340x over previous
//
#include <hip/hip_runtime.h>
#include <hip/hip_bf16.h>
#include <math.h>

// Problem constants
constexpr int kB   = 2;
constexpr int kS   = 2048;
constexpr int kD   = 1024;
constexpr int kFFN = 4096;
constexpr int kM   = kB * kS;      // 4096 tokens
constexpr int kH   = 8;
constexpr int kDH  = 128;
constexpr int kNC  = 64;           // scan chunks
constexpr int kT   = kS / kNC;     // 32 steps per chunk
constexpr int kNE  = 12288;        // 4 experts x 3072 packed N

typedef unsigned short u16;
typedef __attribute__((ext_vector_type(8))) short short8;
typedef __attribute__((ext_vector_type(4))) float f32x4;

__device__ __forceinline__ float sigf(float x) { return 1.0f / (1.0f + __expf(-x)); }
__device__ __forceinline__ float bu2f(u16 u) { return __uint_as_float(((unsigned)u) << 16); }
__device__ __forceinline__ u16 f2bu(float f) {
    __hip_bfloat16 h = __float2bfloat16(f);
    return reinterpret_cast<u16&>(h);
}
__device__ __forceinline__ void async16(const void* g, void* l) {
    __builtin_amdgcn_global_load_lds((const __attribute__((address_space(1))) void*)g,
                                     (__attribute__((address_space(3))) void*)l, 16, 0, 0);
}
// bijective XCD swizzle (m204)
__device__ __forceinline__ int xcd_swz(int orig, int nwg) {
    const int xcd = orig & 7;
    const int q8 = nwg >> 3, r8 = nwg & 7;
    return (xcd < r8 ? xcd * (q8 + 1) : r8 * (q8 + 1) + (xcd - r8) * q8) + (orig >> 3);
}

// ---------------- RMSNorm: f32 in, bf16 out ---------------------------------
__global__ __launch_bounds__(256) void rmsnorm_k(const float* __restrict__ x,
                                                 const float* __restrict__ w,
                                                 u16* __restrict__ o)
{
    __shared__ float red[4];
    const int row = blockIdx.x;
    const int t = threadIdx.x;
    float4 v = ((const float4*)(x + (size_t)row * kD))[t];
    float ss = v.x*v.x + v.y*v.y + v.z*v.z + v.w*v.w;
    #pragma unroll
    for (int m = 32; m; m >>= 1) ss += __shfl_xor(ss, m);
    if ((t & 63) == 0) red[t >> 6] = ss;
    __syncthreads();
    float tot = red[0] + red[1] + red[2] + red[3];
    float r = rsqrtf(tot * (1.0f / (float)kD) + 1e-6f);
    float4 wv = ((const float4*)w)[t];
    ushort4 u;
    u.x = f2bu(v.x * r * wv.x); u.y = f2bu(v.y * r * wv.y);
    u.z = f2bu(v.z * r * wv.z); u.w = f2bu(v.w * r * wv.w);
    ((ushort4*)(o + (size_t)row * kD))[t] = u;
}

// ---------------- Routing: pure f32 from x (top-k must not see bf16) --------
__global__ __launch_bounds__(64) void routing_k(const float* __restrict__ x,
                                                const float* __restrict__ wmix,
                                                const float* __restrict__ gw,
                                                float* __restrict__ wts,
                                                int* __restrict__ idx)
{
    const int row = blockIdx.x;
    const int lane = threadIdx.x;
    const float* xr = x + (size_t)row * kD;
    float ss = 0.0f;
    for (int d = lane; d < kD; d += 64) { float v = xr[d]; ss = fmaf(v, v, ss); }
    #pragma unroll
    for (int m = 32; m; m >>= 1) ss += __shfl_xor(ss, m);
    float r = rsqrtf(ss * (1.0f / (float)kD) + 1e-6f);

    float a0 = 0, a1 = 0, a2 = 0, a3 = 0;
    for (int d = lane; d < kD; d += 64) {
        float xv = xr[d] * wmix[d];
        float4 g = ((const float4*)gw)[d];
        a0 = fmaf(xv, g.x, a0);
        a1 = fmaf(xv, g.y, a1);
        a2 = fmaf(xv, g.z, a2);
        a3 = fmaf(xv, g.w, a3);
    }
    #pragma unroll
    for (int m = 32; m; m >>= 1) {
        a0 += __shfl_xor(a0, m);
        a1 += __shfl_xor(a1, m);
        a2 += __shfl_xor(a2, m);
        a3 += __shfl_xor(a3, m);
    }
    if (lane == 0) {
        float a[4] = {a0, a1, a2, a3};
        int i0 = 0; float v0 = a[0];
        #pragma unroll
        for (int e = 1; e < 4; ++e) if (a[e] > v0) { v0 = a[e]; i0 = e; }
        int i1 = -1; float v1 = -INFINITY;
        #pragma unroll
        for (int e = 0; e < 4; ++e) if (e != i0 && a[e] > v1) { v1 = a[e]; i1 = e; }
        float e1 = __expf(r * (v1 - v0));
        float dn = 1.0f + e1;
        wts[row * 2 + 0] = 1.0f / dn;
        wts[row * 2 + 1] = e1 / dn;
        idx[row * 2 + 0] = i0;
        idx[row * 2 + 1] = i1;
    }
}

// ---------------- prep: ALL weight transposes + bias pack in ONE launch -----
// segments (28720 blocks): [0,12288) Wg/Wv/Wd x4 experts; [12288,15360) qkv;
// [15360,16384) attn_out; [16384,20480) gate; [20480,24576) up;
// [24576,28672) ffn_out; [28672,28720) bias pack.
__global__ __launch_bounds__(256) void prep_k(
    const float* __restrict__ Wg, const float* __restrict__ Wv,
    const float* __restrict__ Wd, const float* __restrict__ wqkv,
    const float* __restrict__ wao, const float* __restrict__ wgate,
    const float* __restrict__ wup, const float* __restrict__ wout,
    const float* __restrict__ bg, const float* __restrict__ bv,
    const float* __restrict__ bd,
    u16* __restrict__ expWT, u16* __restrict__ qkvWT, u16* __restrict__ aoWT,
    u16* __restrict__ gateWT, u16* __restrict__ upWT, u16* __restrict__ outWT,
    float* __restrict__ pbias)
{
    __shared__ float t[32][33];
    const size_t M1 = 1024ull * 1024;
    const int b = blockIdx.x;
    const int tid = threadIdx.x;
    const float* src; u16* dst; int rows, cols, bx, by;

    if (b < 12288) {                      // expert Wg/Wv/Wd (z-batched)
        int seg = b / 4096, local = b % 4096;
        int z = local / 1024, rem = local % 1024;
        const float* W = (seg == 0) ? Wg : (seg == 1) ? Wv : Wd;
        src = W + (size_t)z * kD * kD;
        dst = expWT + (size_t)z * 3 * M1 + (size_t)seg * M1;
        rows = 1024; cols = 1024; bx = rem % 32; by = rem / 32;
    } else if (b < 15360) {               // w_qkv [1024][3072]
        int local = b - 12288;
        src = wqkv; dst = qkvWT; rows = 1024; cols = 3072;
        bx = local % 96; by = local / 96;
    } else if (b < 16384) {               // w_attn_out [1024][1024]
        int local = b - 15360;
        src = wao; dst = aoWT; rows = 1024; cols = 1024;
        bx = local % 32; by = local / 32;
    } else if (b < 20480) {               // w_ffn_gate [1024][4096]
        int local = b - 16384;
        src = wgate; dst = gateWT; rows = 1024; cols = 4096;
        bx = local % 128; by = local / 128;
    } else if (b < 24576) {               // w_ffn_up [1024][4096]
        int local = b - 20480;
        src = wup; dst = upWT; rows = 1024; cols = 4096;
        bx = local % 128; by = local / 128;
    } else if (b < 28672) {               // w_ffn_out [4096][1024]
        int local = b - 24576;
        src = wout; dst = outWT; rows = 4096; cols = 1024;
        bx = local % 32; by = local / 32;
    } else {                              // bias pack [E][3072] = bg|bv|bd
        int local = b - 28672;
        int e = local / 12, rx = local % 12;
        int r = rx * 256 + tid;
        const float* sb = (r < 1024) ? bg : (r < 2048) ? bv : bd;
        pbias[e * 3072 + r] = sb[e * 1024 + (r & 1023)];
        return;
    }

    const int c0 = bx * 32, r0 = by * 32;
    const int tc = tid & 31, tr4 = (tid >> 5) * 4;
    #pragma unroll
    for (int i = 0; i < 4; ++i)
        t[tr4 + i][tc] = src[(size_t)(r0 + tr4 + i) * cols + c0 + tc];
    __syncthreads();
    #pragma unroll
    for (int i = 0; i < 4; ++i) {
        int cc = tr4 + i;
        dst[(size_t)(c0 + cc) * rows + r0 + tc] = f2bu(t[tc][cc]);
    }
}

// ---------------- gemmA: BM=256 BN=256 BK=64, 8 waves (2Mx4N), per-wave 128x64
// R12-verified: 2-buffer double-buffer; __syncthreads per K-tile (issue-early
// loads land under MFMA; wave-level overlap hides the drain). Zero-conflict
// swizzle. M-fastest XCD mapping -> B panel L2-resident.
template<bool BIAS, bool SILU, bool MUL>
__global__ __launch_bounds__(512, 2) void gemmA_k(
    const u16* __restrict__ A, const u16* __restrict__ BT,
    const float* __restrict__ bias, const u16* __restrict__ mulsrc,
    u16* __restrict__ Cout, int N, int K)
{
    __shared__ __align__(16) u16 lds[2][32768];   // per stage: A[256][64] | B[256][64]
    const int tid = threadIdx.x;
    const int l = tid & 63;
    const int w = tid >> 6;                 // 0..7
    const int wr = w >> 2, wc = w & 3;      // 2M x 4N
    const int fr = l & 15, g = l >> 4;

    const int my = gridDim.y;               // M blocks
    const int wg = xcd_swz(blockIdx.y * gridDim.x + blockIdx.x, gridDim.x * my);
    const int bm = (wg % my) * 256, bn = (wg / my) * 256;   // M-fastest

    const int srow = l >> 3;
    const int scol = (l & 7) ^ srow;        // pre-swizzled source col-chunk
    const u16* gA = A  + (size_t)(bm + srow) * K + scol * 8;
    const u16* gB = BT + (size_t)(bn + srow) * K + scol * 8;

    auto STAGE = [&](int kt, int sb) {
        u16* dst = lds[sb] + l * 8;
        const int k0 = kt * 64;
        #pragma unroll
        for (int i = 0; i < 4; ++i) {
            int chunk = w * 4 + i;
            async16(gA + (size_t)chunk * 8 * K + k0, dst + chunk * 512);
            async16(gB + (size_t)chunk * 8 * K + k0, dst + 16384 + chunk * 512);
        }
    };

    f32x4 acc[8][4];
    #pragma unroll
    for (int m = 0; m < 8; ++m)
        #pragma unroll
        for (int n = 0; n < 4; ++n) acc[m][n] = (f32x4){0.f, 0.f, 0.f, 0.f};

    STAGE(0, 0);
    __syncthreads();
    const int nt = K >> 6;
    for (int t = 0; t < nt; ++t) {
        const int cb = t & 1;
        if (t + 1 < nt) STAGE(t + 1, cb ^ 1);   // issue-early; lands under MFMA
        const u16* bA = lds[cb];
        const u16* bB = lds[cb] + 16384;
        #pragma unroll
        for (int ks = 0; ks < 2; ++ks) {
            const int xo = ((ks * 4 + g) ^ (fr & 7)) * 8;
            short8 b[4];
            #pragma unroll
            for (int n = 0; n < 4; ++n)
                b[n] = *(const short8*)(bB + (wc * 64 + n * 16 + fr) * 64 + xo);
            #pragma unroll
            for (int m = 0; m < 8; ++m) {
                short8 a = *(const short8*)(bA + (wr * 128 + m * 16 + fr) * 64 + xo);
                #pragma unroll
                for (int n = 0; n < 4; ++n)
                    acc[m][n] = __builtin_amdgcn_mfma_f32_16x16x32_bf16(a, b[n], acc[m][n], 0, 0, 0);
            }
        }
        __syncthreads();   // drains t+1 loads; guards buf reuse
    }

    const int orow0 = bm + wr * 128 + g * 4;
    const int ocol0 = bn + wc * 64 + fr;
    float bi[4];
    if constexpr (BIAS) {
        #pragma unroll
        for (int n = 0; n < 4; ++n) bi[n] = bias[ocol0 + n * 16];
    }
    #pragma unroll
    for (int m = 0; m < 8; ++m) {
        #pragma unroll
        for (int r = 0; r < 4; ++r) {
            const size_t ro = (size_t)(orow0 + m * 16 + r) * N;
            #pragma unroll
            for (int n = 0; n < 4; ++n) {
                const size_t off = ro + ocol0 + n * 16;
                float v = acc[m][n][r];
                if constexpr (BIAS) v += bi[n];
                if constexpr (SILU) v = v * sigf(v);
                if constexpr (MUL)  v *= bu2f(mulsrc[off]);
                Cout[off] = f2bu(v);
            }
        }
    }
}

// ---------------- gemmGU: fused FFN gate+up dual GEMM -----------------------
__global__ __launch_bounds__(512, 2) void gemmGU_k(
    const u16* __restrict__ A, const u16* __restrict__ GT,
    const u16* __restrict__ UT, u16* __restrict__ Cout, int N, int K)
{
    __shared__ __align__(16) u16 ldsA[2][16384];   // A[256][64]
    __shared__ __align__(16) u16 ldsG[2][8192];    // gate[128][64]
    __shared__ __align__(16) u16 ldsU[2][8192];    // up  [128][64]
    const int tid = threadIdx.x;
    const int l = tid & 63;
    const int w = tid >> 6;                 // 0..7
    const int wr = w >> 2, wc = w & 3;      // 2M x 4N (N in 32-col slots)
    const int fr = l & 15, g = l >> 4;

    const int my = gridDim.y;
    const int wg = xcd_swz(blockIdx.y * gridDim.x + blockIdx.x, gridDim.x * my);
    const int bm = (wg % my) * 256, bn = (wg / my) * 128;   // M-fastest

    const int srow = l >> 3;
    const int scol = (l & 7) ^ srow;
    const u16* gA = A  + (size_t)(bm + srow) * K + scol * 8;
    const u16* gG = GT + (size_t)(bn + srow) * K + scol * 8;
    const u16* gU = UT + (size_t)(bn + srow) * K + scol * 8;

    auto STAGE = [&](int kt, int sb) {      // 8 async16/thread (A4 + G2 + U2)
        const int k0 = kt * 64;
        u16* dA = ldsA[sb] + l * 8;
        #pragma unroll
        for (int i = 0; i < 4; ++i) {
            int chunk = w * 4 + i;
            async16(gA + (size_t)chunk * 8 * K + k0, dA + chunk * 512);
        }
        u16* dG = ldsG[sb] + l * 8;
        u16* dU = ldsU[sb] + l * 8;
        #pragma unroll
        for (int i = 0; i < 2; ++i) {
            int chunk = w * 2 + i;          // 16 chunks of 8 rows = 128 rows
            async16(gG + (size_t)chunk * 8 * K + k0, dG + chunk * 512);
            async16(gU + (size_t)chunk * 8 * K + k0, dU + chunk * 512);
        }
    };

    f32x4 accg[8][2], accu[8][2];
    #pragma unroll
    for (int m = 0; m < 8; ++m)
        #pragma unroll
        for (int n = 0; n < 2; ++n) {
            accg[m][n] = (f32x4){0.f, 0.f, 0.f, 0.f};
            accu[m][n] = (f32x4){0.f, 0.f, 0.f, 0.f};
        }

    STAGE(0, 0);
    __syncthreads();
    const int nt = K >> 6;
    for (int t = 0; t < nt; ++t) {
        const int cb = t & 1;
        if (t + 1 < nt) STAGE(t + 1, cb ^ 1);
        const u16* bA = ldsA[cb];
        const u16* bG = ldsG[cb];
        const u16* bU = ldsU[cb];
        #pragma unroll
        for (int ks = 0; ks < 2; ++ks) {
            const int xo = ((ks * 4 + g) ^ (fr & 7)) * 8;
            short8 vg[2], vu[2];
            #pragma unroll
            for (int n = 0; n < 2; ++n) {
                vg[n] = *(const short8*)(bG + (wc * 32 + n * 16 + fr) * 64 + xo);
                vu[n] = *(const short8*)(bU + (wc * 32 + n * 16 + fr) * 64 + xo);
            }
            #pragma unroll
            for (int m = 0; m < 8; ++m) {
                short8 a = *(const short8*)(bA + (wr * 128 + m * 16 + fr) * 64 + xo);
                #pragma unroll
                for (int n = 0; n < 2; ++n) {
                    accg[m][n] = __builtin_amdgcn_mfma_f32_16x16x32_bf16(a, vg[n], accg[m][n], 0, 0, 0);
                    accu[m][n] = __builtin_amdgcn_mfma_f32_16x16x32_bf16(a, vu[n], accu[m][n], 0, 0, 0);
                }
            }
        }
        __syncthreads();
    }

    const int orow0 = bm + wr * 128 + g * 4;
    const int ocol0 = bn + wc * 32 + fr;
    #pragma unroll
    for (int m = 0; m < 8; ++m) {
        #pragma unroll
        for (int r = 0; r < 4; ++r) {
            const size_t ro = (size_t)(orow0 + m * 16 + r) * N;
            #pragma unroll
            for (int n = 0; n < 2; ++n) {
                float gv = accg[m][n][r];
                float uv = accu[m][n][r];
                Cout[ro + ocol0 + n * 16] = f2bu(gv * sigf(gv) * uv);
            }
        }
    }
}

// ---------------- gemmO: BM=256 BN=64 BK=64, 8 waves (4Mx2N), 2-stage --------
__global__ __launch_bounds__(512, 2) void gemmO_k(
    const u16* __restrict__ A, const u16* __restrict__ BT,
    const float* __restrict__ res, float* __restrict__ Cout,
    int N, int K)
{
    __shared__ __align__(16) u16 lds[2][20480];   // per stage: A[256][64] | B[64][64]
    const int tid = threadIdx.x;
    const int l = tid & 63;
    const int w = tid >> 6;                 // 0..7
    const int wr = w >> 1, wc = w & 1;      // 4M x 2N; per-wave 64x32
    const int fr = l & 15, g = l >> 4;

    const int my = gridDim.y;
    const int wg = xcd_swz(blockIdx.y * gridDim.x + blockIdx.x, gridDim.x * my);
    const int bm = (wg % my) * 256, bn = (wg / my) * 64;    // M-fastest

    const int srow = l >> 3;
    const int scol = (l & 7) ^ srow;
    const u16* gA = A  + (size_t)(bm + srow) * K + scol * 8;
    const u16* gB = BT + (size_t)(bn + srow) * K + scol * 8;

    auto STAGE = [&](int kt, int sb) {
        u16* dst = lds[sb] + l * 8;
        const int k0 = kt * 64;
        #pragma unroll
        for (int i = 0; i < 4; ++i) {       // A: 32 chunks / 8 waves
            int chunk = w * 4 + i;
            async16(gA + (size_t)chunk * 8 * K + k0, dst + chunk * 512);
        }
        // B: 8 chunks / 8 waves (1 each)
        async16(gB + (size_t)w * 8 * K + k0, dst + 16384 + w * 512);
    };

    f32x4 acc[4][2];
    #pragma unroll
    for (int m = 0; m < 4; ++m)
        #pragma unroll
        for (int n = 0; n < 2; ++n) acc[m][n] = (f32x4){0.f, 0.f, 0.f, 0.f};

    STAGE(0, 0);
    __syncthreads();
    const int nt = K >> 6;
    for (int t = 0; t < nt; ++t) {
        const int cb = t & 1;
        if (t + 1 < nt) STAGE(t + 1, cb ^ 1);
        const u16* bA = lds[cb];
        const u16* bB = lds[cb] + 16384;
        #pragma unroll
        for (int ks = 0; ks < 2; ++ks) {
            const int xo = ((ks * 4 + g) ^ (fr & 7)) * 8;
            short8 a[4], b[2];
            #pragma unroll
            for (int m = 0; m < 4; ++m)
                a[m] = *(const short8*)(bA + (wr * 64 + m * 16 + fr) * 64 + xo);
            #pragma unroll
            for (int n = 0; n < 2; ++n)
                b[n] = *(const short8*)(bB + (wc * 32 + n * 16 + fr) * 64 + xo);
            #pragma unroll
            for (int m = 0; m < 4; ++m)
                #pragma unroll
                for (int n = 0; n < 2; ++n)
                    acc[m][n] = __builtin_amdgcn_mfma_f32_16x16x32_bf16(a[m], b[n], acc[m][n], 0, 0, 0);
        }
        __syncthreads();
    }

    const int orow0 = bm + wr * 64 + g * 4;
    const int ocol0 = bn + wc * 32 + fr;
    #pragma unroll
    for (int m = 0; m < 4; ++m) {
        #pragma unroll
        for (int r = 0; r < 4; ++r) {
            const size_t ro = (size_t)(orow0 + m * 16 + r) * N;
            #pragma unroll
            for (int n = 0; n < 2; ++n) {
                const size_t off = ro + ocol0 + n * 16;
                Cout[off] = acc[m][n][r] + res[off];
            }
        }
    }
}

// ---------------- minGRU chunked scan over gvdall [M][12288] ----------------
__global__ __launch_bounds__(256) void scan1_k(const u16* __restrict__ gvdall,
                                               float* __restrict__ sumA,
                                               float* __restrict__ sumX)
{
    const int e = blockIdx.y;
    int i = blockIdx.x * 256 + threadIdx.x;      // [0, kB*kNC*kD)
    int d = i & (kD - 1);
    int c = (i >> 10) & (kNC - 1);
    int b = i >> 16;
    const u16* gvd = gvdall + e * 3072;
    size_t base = ((size_t)b * kS + c * kT) * kNE + d;
    float A = 1.0f, X = 0.0f;
    for (int t = 0; t < kT; ++t) {
        size_t ix = base + (size_t)t * kNE;
        float xs = sigf(bu2f(gvd[ix])) * tanhf(bu2f(gvd[ix + 1024]));
        float a  = 0.001f + 0.998f * sigf(bu2f(gvd[ix + 2048]));
        A *= a;
        X = fmaf(a, X, xs);
    }
    size_t si = ((size_t)(e * kNC + c) * kB + b) * kD + d;
    sumA[si] = A;
    sumX[si] = X;
}

__global__ __launch_bounds__(256) void scan2_k(const float* __restrict__ sumA,
                                               const float* __restrict__ sumX,
                                               float* __restrict__ carry)
{
    const int e = blockIdx.y;
    int bd = blockIdx.x * 256 + threadIdx.x;     // [0, kB*kD)
    float h = 0.0f;
    for (int c = 0; c < kNC; ++c) {
        size_t si = ((size_t)(e * kNC + c)) * (kB * kD) + bd;
        carry[si] = h;
        h = fmaf(sumA[si], h, sumX[si]);
    }
}

// scan3: write h ONLY for the token's 2 selected experts (slot buffers)
__global__ __launch_bounds__(256) void scan3_k(const u16* __restrict__ gvdall,
                                               const float* __restrict__ carry,
                                               const int* __restrict__ tidx,
                                               u16* __restrict__ slot0,
                                               u16* __restrict__ slot1)
{
    const int e = blockIdx.y;
    int i = blockIdx.x * 256 + threadIdx.x;
    int d = i & (kD - 1);
    int c = (i >> 10) & (kNC - 1);
    int b = i >> 16;
    const u16* gvd = gvdall + e * 3072;
    size_t base = ((size_t)b * kS + c * kT) * kNE + d;
    float h = carry[((size_t)(e * kNC + c) * kB + b) * kD + d];
    const int tok0 = b * kS + c * kT;
    for (int t = 0; t < kT; ++t) {
        size_t ix = base + (size_t)t * kNE;
        float xs = sigf(bu2f(gvd[ix])) * tanhf(bu2f(gvd[ix + 1024]));
        float a  = 0.001f + 0.998f * sigf(bu2f(gvd[ix + 2048]));
        h = fmaf(a, h, xs);
        const int tok = tok0 + t;
        const size_t o = (size_t)tok * kD + d;
        if (e == tidx[tok * 2])          slot0[o] = f2bu(h);
        else if (e == tidx[tok * 2 + 1]) slot1[o] = f2bu(h);
    }
}

// ---------------- Fused MoE mix + attn RMSNorm -------------------------------
__global__ __launch_bounds__(256) void mixrms_k(const float* __restrict__ x,
                                                const u16* __restrict__ slot0,
                                                const u16* __restrict__ slot1,
                                                const float* __restrict__ wts,
                                                const float* __restrict__ w,
                                                float* __restrict__ xo,
                                                u16* __restrict__ xn)
{
    __shared__ float red[4];
    const int row = blockIdx.x;
    const int t = threadIdx.x;
    const size_t i = (size_t)row * 256 + t;     // float4 index
    float w0 = wts[row * 2 + 0], w1 = wts[row * 2 + 1];
    float4 xv = ((const float4*)x)[i];
    ushort4 h0 = ((const ushort4*)slot0)[i];
    ushort4 h1 = ((const ushort4*)slot1)[i];
    float4 o;
    o.x = xv.x + w0 * bu2f(h0.x) + w1 * bu2f(h1.x);
    o.y = xv.y + w0 * bu2f(h0.y) + w1 * bu2f(h1.y);
    o.z = xv.z + w0 * bu2f(h0.z) + w1 * bu2f(h1.z);
    o.w = xv.w + w0 * bu2f(h0.w) + w1 * bu2f(h1.w);
    ((float4*)xo)[i] = o;

    float ss = o.x*o.x + o.y*o.y + o.z*o.z + o.w*o.w;
    #pragma unroll
    for (int m = 32; m; m >>= 1) ss += __shfl_xor(ss, m);
    if ((t & 63) == 0) red[t >> 6] = ss;
    __syncthreads();
    float tot = red[0] + red[1] + red[2] + red[3];
    float r = rsqrtf(tot * (1.0f / (float)kD) + 1e-6f);
    float4 wv = ((const float4*)w)[t];
    ushort4 u;
    u.x = f2bu(o.x * r * wv.x); u.y = f2bu(o.y * r * wv.y);
    u.z = f2bu(o.z * r * wv.z); u.w = f2bu(o.w * r * wv.w);
    ((ushort4*)(xn + (size_t)row * kD))[t] = u;
}

// ---------------- V transpose: qkvb V-part -> vT [b*H+h][128 d][2048 s] -----
__global__ __launch_bounds__(256) void transpV_k(const u16* __restrict__ qkvb,
                                                 u16* __restrict__ vT)
{
    __shared__ u16 t[64][68];
    const int tid = threadIdx.x;
    const int s0 = blockIdx.x * 64;
    const int d0 = blockIdx.y * 64;
    const int bh = blockIdx.z;
    const int bb = bh >> 3, hh = bh & 7;
    const u16* src = qkvb + (size_t)(bb * kS + s0) * 3072 + 2048 + hh * kDH + d0;
    for (int idx = tid; idx < 64 * 16; idx += 256) {
        int sl = idx >> 4, c4 = (idx & 15) * 4;
        *(ushort4*)&t[sl][c4] = *(const ushort4*)(src + (size_t)sl * 3072 + c4);
    }
    __syncthreads();
    u16* dst = vT + ((size_t)bh * kDH + d0) * kS + s0;
    for (int idx = tid; idx < 64 * 16; idx += 256) {
        int dl = idx >> 4, s4 = (idx & 15) * 4;
        ushort4 v;
        v.x = t[s4 + 0][dl]; v.y = t[s4 + 1][dl];
        v.z = t[s4 + 2][dl]; v.w = t[s4 + 3][dl];
        *(ushort4*)(dst + (size_t)dl * kS + s4) = v;
    }
}

// ---------------- MFMA sliding-window attention ------------------------------
__global__ __launch_bounds__(256) void attn_mfma_k(const u16* __restrict__ qkvb,
                                                   const u16* __restrict__ vT,
                                                   u16* __restrict__ aob)
{
    __shared__ __align__(16) u16 KV[26112];      // K: [192][136] | VT: [128][200]
    __shared__ __align__(16) u16 P[4 * 16 * 200];

    const int tid = threadIdx.x;
    const int lane = tid & 63;
    const int w = tid >> 6;
    const int fr = lane & 15, g = lane >> 4;
    const int q0 = blockIdx.x * 64;
    const int hh = blockIdx.y;
    const int bb = blockIdx.z;
    const int kbase = q0 - 128;
    const float scale = 0.08838834764831845f;    // 1/sqrt(128)

    const u16* qkv_b = qkvb + (size_t)bb * kS * 3072 + hh * kDH;

    for (int idx = tid; idx < 192 * 16; idx += 256) {
        int k = idx >> 4, c = idx & 15;
        int kg = kbase + k; if (kg < 0) kg = 0;
        short8 v = *(const short8*)(qkv_b + (size_t)kg * 3072 + 1024 + c * 8);
        *(short8*)(&KV[k * 136 + c * 8]) = v;
    }
    short8 qf[4];
    {
        const u16* qrow = qkv_b + (size_t)(q0 + w * 16 + fr) * 3072 + g * 8;
        #pragma unroll
        for (int s = 0; s < 4; ++s) qf[s] = *(const short8*)(qrow + s * 32);
    }
    __syncthreads();

    f32x4 sacc[12];
    #pragma unroll
    for (int f = 0; f < 12; ++f) sacc[f] = (f32x4){0.f, 0.f, 0.f, 0.f};
    #pragma unroll
    for (int s = 0; s < 4; ++s) {
        #pragma unroll
        for (int f = 0; f < 12; ++f) {
            short8 bfr = *(const short8*)(&KV[(f * 16 + fr) * 136 + s * 32 + g * 8]);
            sacc[f] = __builtin_amdgcn_mfma_f32_16x16x32_bf16(qf[s], bfr, sacc[f], 0, 0, 0);
        }
    }

    float p[12][4];
    #pragma unroll
    for (int r = 0; r < 4; ++r) {
        const int ql = w * 16 + g * 4 + r;
        int kmin = 128 - q0; if (kmin < ql + 1) kmin = ql + 1;
        const int kmax = ql + 128;
        float mx = -1e30f;
        #pragma unroll
        for (int f = 0; f < 12; ++f) {
            int kl = f * 16 + fr;
            float sv = (kl >= kmin && kl <= kmax) ? sacc[f][r] * scale : -1e30f;
            p[f][r] = sv;
            mx = fmaxf(mx, sv);
        }
        mx = fmaxf(mx, __shfl_xor(mx, 1));
        mx = fmaxf(mx, __shfl_xor(mx, 2));
        mx = fmaxf(mx, __shfl_xor(mx, 4));
        mx = fmaxf(mx, __shfl_xor(mx, 8));
        float l = 0.f;
        #pragma unroll
        for (int f = 0; f < 12; ++f) { float e = __expf(p[f][r] - mx); p[f][r] = e; l += e; }
        l += __shfl_xor(l, 1);
        l += __shfl_xor(l, 2);
        l += __shfl_xor(l, 4);
        l += __shfl_xor(l, 8);
        float linv = 1.0f / l;
        #pragma unroll
        for (int f = 0; f < 12; ++f) p[f][r] *= linv;
    }

    {
        u16* pw = &P[(w * 16) * 200];
        #pragma unroll
        for (int r = 0; r < 4; ++r)
            #pragma unroll
            for (int f = 0; f < 12; ++f)
                pw[(g * 4 + r) * 200 + f * 16 + fr] = f2bu(p[f][r]);
    }
    __syncthreads();

    {
        const u16* vrow = vT + (size_t)(bb * kH + hh) * kDH * kS;
        for (int idx = tid; idx < 128 * 25; idx += 256) {
            int d = idx / 25, c = idx % 25;
            if (c < 24) {
                int s0k = kbase + c * 8;
                short8 v;
                if (s0k < 0) v = (short8){0, 0, 0, 0, 0, 0, 0, 0};
                else v = *(const short8*)(vrow + (size_t)d * kS + s0k);
                *(short8*)(&KV[d * 200 + c * 8]) = v;
            }
        }
    }
    __syncthreads();

    f32x4 oacc[8];
    #pragma unroll
    for (int f = 0; f < 8; ++f) oacc[f] = (f32x4){0.f, 0.f, 0.f, 0.f};
    const u16* pr = &P[(w * 16 + fr) * 200 + g * 8];
    #pragma unroll
    for (int s = 0; s < 6; ++s) {
        short8 afr = *(const short8*)(pr + s * 32);
        #pragma unroll
        for (int f = 0; f < 8; ++f) {
            short8 bfr = *(const short8*)(&KV[(f * 16 + fr) * 200 + s * 32 + g * 8]);
            oacc[f] = __builtin_amdgcn_mfma_f32_16x16x32_bf16(afr, bfr, oacc[f], 0, 0, 0);
        }
    }
    u16* orow = aob + ((size_t)(bb * kS + q0 + w * 16 + g * 4) * kD) + hh * kDH + fr;
    #pragma unroll
    for (int r = 0; r < 4; ++r)
        #pragma unroll
        for (int f = 0; f < 8; ++f)
            orow[(size_t)r * kD + f * 16] = f2bu(oacc[f][r]);
}

// ---------------------------------------------------------------------------
extern "C" void kernel_launch(void* const* d_in, const int* in_sizes, int n_in,
                              void* d_out, int out_size, void* d_ws, size_t ws_size,
                              hipStream_t stream)
{
    (void)in_sizes; (void)n_in; (void)out_size; (void)ws_size;

    const float* x          = (const float*)d_in[0];
    const float* rms_mix    = (const float*)d_in[1];
    const float* gate_w     = (const float*)d_in[2];
    const float* Wg         = (const float*)d_in[3];
    const float* bg         = (const float*)d_in[4];
    const float* Wv         = (const float*)d_in[5];
    const float* bv         = (const float*)d_in[6];
    const float* Wd         = (const float*)d_in[7];
    const float* bd         = (const float*)d_in[8];
    const float* rms_attn   = (const float*)d_in[9];
    const float* w_qkv      = (const float*)d_in[10];
    const float* w_attn_out = (const float*)d_in[11];
    const float* rms_ffn    = (const float*)d_in[12];
    const float* w_ffn_gate = (const float*)d_in[13];
    const float* w_ffn_up   = (const float*)d_in[14];
    const float* w_ffn_out  = (const float*)d_in[15];
    float* out = (float*)d_out;

    const size_t MD = (size_t)kM * kD;
    const size_t M1 = 1024ull * 1024;
    char* p = (char*)d_ws;
    auto take = [&](size_t n) { char* r = p; p += (n + 255) & ~(size_t)255; return r; };

    u16*   xnb    = (u16*)take(MD * 2);                     // 8.4 MB
    u16*   gvdall = (u16*)take((size_t)kM * kNE * 2);       // 100.7 MB: gvd | qkvb | hidB
    u16*   qkvb   = gvdall;
    u16*   hidB   = gvdall + (size_t)kM * kFFN;
    u16*   ehb    = (u16*)take(4 * MD * 2);                 // 33.6 MB: slots|aob+vT + gate/up WT
    u16*   slot0  = ehb;
    u16*   slot1  = ehb + MD;
    u16*   aob    = ehb;
    u16*   vTb    = ehb + MD;
    u16*   gateWT = ehb + 2 * MD;                           // spare upper half (4 M1)
    u16*   upWT   = gateWT + 4 * M1;                        // (4 M1)
    u16*   wbuf   = (u16*)take(20ull * M1 * 2);             // 40 MB: exp12|qkv3|ao1|out4
    u16*   qkvWT  = wbuf + 12 * M1;
    u16*   aoWT   = wbuf + 15 * M1;
    u16*   outWT  = wbuf + 16 * M1;
    float* pbias  = (float*)take((size_t)kNE * 4);
    float* sumA   = (float*)take(4ull * kNC * kB * kD * 4);
    float* sumX   = (float*)take(4ull * kNC * kB * kD * 4);
    float* carry  = (float*)take(4ull * kNC * kB * kD * 4);
    float* wts    = (float*)take((size_t)2 * kM * 4);
    int*   tidx   = (int*)take((size_t)2 * kM * 4);

    const dim3 blk(256);

    // ---- ONE prep launch: all weight transposes + bias pack ----
    prep_k<<<28720, blk, 0, stream>>>(Wg, Wv, Wd, w_qkv, w_attn_out,
                                      w_ffn_gate, w_ffn_up, w_ffn_out,
                                      bg, bv, bd,
                                      wbuf, qkvWT, aoWT, gateWT, upWT, outWT, pbias);

    // ---- stage 1: rmsnorm + routing ----
    rmsnorm_k<<<kM, blk, 0, stream>>>(x, rms_mix, xnb);
    routing_k<<<kM, dim3(64), 0, stream>>>(x, rms_mix, gate_w, wts, tidx);

    // ---- experts: ONE batched GEMM (N=12288) + z-batched scans ----
    gemmA_k<true, false, false><<<dim3(kNE / 256, kM / 256), dim3(512), 0, stream>>>(
        xnb, wbuf, pbias, nullptr, gvdall, kNE, 1024);
    const int scan_blocks = kB * kD * kNC / 256;
    scan1_k<<<dim3(scan_blocks, 4), blk, 0, stream>>>(gvdall, sumA, sumX);
    scan2_k<<<dim3(kB * kD / 256, 4), blk, 0, stream>>>(sumA, sumX, carry);
    scan3_k<<<dim3(scan_blocks, 4), blk, 0, stream>>>(gvdall, carry, tidx, slot0, slot1);

    // ---- MoE mix + attn rmsnorm (fused) -> out (x1), xnb ----
    mixrms_k<<<kM, blk, 0, stream>>>(x, slot0, slot1, wts, rms_attn, out, xnb);

    // ---- attention ----
    gemmA_k<false, false, false><<<dim3(3072 / 256, kM / 256), dim3(512), 0, stream>>>(
        xnb, qkvWT, nullptr, nullptr, qkvb, 3072, 1024);
    transpV_k<<<dim3(kS / 64, 2, kB * kH), blk, 0, stream>>>(qkvb, vTb);
    attn_mfma_k<<<dim3(kS / 64, kH, kB), blk, 0, stream>>>(qkvb, vTb, aob);
    gemmO_k<<<dim3(1024 / 64, kM / 256), dim3(512), 0, stream>>>(
        aob, aoWT, out, out, 1024, 1024);

    // ---- FFN: fused gate+up (dual), then out proj ----
    rmsnorm_k<<<kM, blk, 0, stream>>>(out, rms_ffn, xnb);
    gemmGU_k<<<dim3(kFFN / 128, kM / 256), dim3(512), 0, stream>>>(
        xnb, gateWT, upWT, hidB, kFFN, 1024);
    gemmO_k<<<dim3(1024 / 64, kM / 256), dim3(512), 0, stream>>>(
        hidB, outWT, out, out, 1024, 4096);
}